// Round 1
// baseline (407.027 us; speedup 1.0000x reference)
//
#include <hip/hip_runtime.h>
#include <stdint.h>

#define BB 8
#define CC 512
#define NN 2304
#define PP 64

typedef float f32x4 __attribute__((ext_vector_type(4)));
typedef short s16x8 __attribute__((ext_vector_type(8)));

__device__ __forceinline__ unsigned short f2bf(float f) {
  union { float f; uint32_t u; } v; v.f = f;
  uint32_t u = v.u;
  return (unsigned short)((u + 0x7FFFu + ((u >> 16) & 1u)) >> 16);
}
__device__ __forceinline__ float bf2f(unsigned short b) {
  union { uint32_t u; float f; } v; v.u = ((uint32_t)b) << 16;
  return v.f;
}

// ---------------- prep: bf16 weight concat [Wq|Wk|Wv] rows + Wfc ----------------
__global__ void k_prep_w(const float* __restrict__ Wq, const float* __restrict__ Wk,
                         const float* __restrict__ Wv, const float* __restrict__ Wfc,
                         unsigned short* __restrict__ wcat, unsigned short* __restrict__ wfc16) {
  int idx = blockIdx.x * 256 + threadIdx.x;
  const int tot_cat = 640 * 512;
  const int total = tot_cat + 512 * 512;
  if (idx >= total) return;
  if (idx < tot_cat) {
    int j = idx >> 9, k = idx & 511;
    float v = (j < 64) ? Wq[j * 512 + k] : ((j < 128) ? Wk[(j - 64) * 512 + k] : Wv[(j - 128) * 512 + k]);
    wcat[idx] = f2bf(v);
  } else {
    int i2 = idx - tot_cat;
    wfc16[i2] = f2bf(Wfc[i2]);
  }
}

// ---------------- px16[b][n][c] = bf16(x[b][c][n]) ----------------
__global__ void k_px(const float* __restrict__ x, unsigned short* __restrict__ px16) {
  __shared__ float t[32][33];
  int b = blockIdx.x;
  int nb = blockIdx.y * 32;
  int cb = blockIdx.z * 32;
  int lane = threadIdx.x & 31;
  int row = threadIdx.x >> 5;  // 0..7
  const float* xb = x + (size_t)b * CC * NN;
  for (int rr = 0; rr < 4; rr++) {
    int c = cb + row + 8 * rr;
    t[row + 8 * rr][lane] = xb[(size_t)c * NN + nb + lane];
  }
  __syncthreads();
  unsigned short* pb = px16 + (size_t)b * NN * CC;
  for (int rr = 0; rr < 4; rr++) {
    int n = nb + row + 8 * rr;
    pb[(size_t)n * CC + cb + lane] = f2bf(t[lane][row + 8 * rr]);
  }
}

// ---------------- QKV GEMM: qkv[b][n][j], j<64: tanh*align_w, j<128: tanh, else v ----------------
__global__ __launch_bounds__(256, 2) void k_qkv(const unsigned short* __restrict__ px16,
                                                const unsigned short* __restrict__ wcat,
                                                const float* __restrict__ align_w,
                                                unsigned short* __restrict__ qkv) {
  int b = blockIdx.x;
  int nb = blockIdx.y * 64;
  int jb0 = blockIdx.z * 128;
  int tid = threadIdx.x;
  int w = tid >> 6, l = tid & 63, l15 = l & 15, lq = l >> 4;
  int jw = jb0 + 32 * w;
  const unsigned short* A = px16 + ((size_t)b * NN + nb) * CC;  // [64][512]
  f32x4 acc[4][2];
  for (int mf = 0; mf < 4; mf++) for (int nf = 0; nf < 2; nf++) acc[mf][nf] = (f32x4){0.f, 0.f, 0.f, 0.f};
  for (int kk = 0; kk < 16; kk++) {
    int k0 = kk * 32 + 8 * lq;
    s16x8 a[4], bb[2];
    for (int mf = 0; mf < 4; mf++)
      a[mf] = *(const s16x8*)(A + (size_t)(16 * mf + l15) * CC + k0);
    for (int nf = 0; nf < 2; nf++)
      bb[nf] = *(const s16x8*)(wcat + (size_t)(jw + 16 * nf + l15) * CC + k0);
    for (int mf = 0; mf < 4; mf++)
      for (int nf = 0; nf < 2; nf++)
        acc[mf][nf] = __builtin_amdgcn_mfma_f32_16x16x32_bf16(a[mf], bb[nf], acc[mf][nf], 0, 0, 0);
  }
  unsigned short* O = qkv + ((size_t)b * NN + nb) * 640;
  for (int mf = 0; mf < 4; mf++)
    for (int nf = 0; nf < 2; nf++)
      for (int r = 0; r < 4; r++) {
        int n = 16 * mf + 4 * lq + r;
        int j = jw + 16 * nf + l15;
        float v = acc[mf][nf][r];
        if (j < 128) { v = tanhf(v); if (j < 64) v *= align_w[j]; }
        O[(size_t)n * 640 + j] = f2bf(v);
      }
}

// ---------------- vt16[b][c][n] = v part of qkv (transpose) ----------------
__global__ void k_vt(const unsigned short* __restrict__ qkv, unsigned short* __restrict__ vt) {
  __shared__ uint32_t t[32][33];
  int b = blockIdx.x;
  int nb = blockIdx.y * 32;
  int cb = blockIdx.z * 32;
  int lane = threadIdx.x & 31;
  int row = threadIdx.x >> 5;
  const unsigned short* src = qkv + (size_t)b * NN * 640 + 128;
  for (int rr = 0; rr < 4; rr++) {
    int n = nb + row + 8 * rr;
    t[row + 8 * rr][lane] = (uint32_t)src[(size_t)n * 640 + cb + lane];
  }
  __syncthreads();
  unsigned short* dst = vt + (size_t)b * CC * NN;
  for (int rr = 0; rr < 4; rr++) {
    int c = cb + row + 8 * rr;
    dst[(size_t)c * NN + nb + lane] = (unsigned short)t[lane][row + 8 * rr];
  }
}

// ---------------- fused attention: content[b][n][c] = px + softmax(qa k^T) v ----------------
// i-tile = 32 rows, 4 waves: scores j-slice 16/wave, PV c-slice 128/wave.
__global__ __launch_bounds__(256, 2) void k_attn(const unsigned short* __restrict__ qkv,
                                                 const unsigned short* __restrict__ vt,
                                                 unsigned short* __restrict__ content /* aliases px16 */) {
  __shared__ __align__(16) unsigned short e_s[32 * 64];  // XOR-swizzled
  __shared__ float rs_s[4][32];
  int b = blockIdx.x;
  int ib = blockIdx.y * 32;
  int tid = threadIdx.x;
  int w = tid >> 6, l = tid & 63, l15 = l & 15, lq = l >> 4;
  const unsigned short* qkvb = qkv + (size_t)b * NN * 640;
  const unsigned short* kbase = qkvb + 64;
  const unsigned short* vtb = vt + (size_t)b * CC * NN;

  s16x8 qa[2][2];
  for (int mf = 0; mf < 2; mf++)
    for (int ks = 0; ks < 2; ks++)
      qa[mf][ks] = *(const s16x8*)(qkvb + (size_t)(ib + 16 * mf + l15) * 640 + 32 * ks + 8 * lq);

  f32x4 acc[2][8];
  for (int mf = 0; mf < 2; mf++) for (int nf = 0; nf < 8; nf++) acc[mf][nf] = (f32x4){0.f, 0.f, 0.f, 0.f};
  float rs[2][4];
  for (int mf = 0; mf < 2; mf++) for (int r = 0; r < 4; r++) rs[mf][r] = 0.f;

  for (int jt = 0; jt < NN / 64; jt++) {
    int jb = jt * 64;
    // scores for wave's 16-j slice
    f32x4 sc[2];
    sc[0] = (f32x4){0.f, 0.f, 0.f, 0.f};
    sc[1] = (f32x4){0.f, 0.f, 0.f, 0.f};
    for (int ks = 0; ks < 2; ks++) {
      s16x8 kf = *(const s16x8*)(kbase + (size_t)(jb + 16 * w + l15) * 640 + 32 * ks + 8 * lq);
      for (int mf = 0; mf < 2; mf++)
        sc[mf] = __builtin_amdgcn_mfma_f32_16x16x32_bf16(qa[mf][ks], kf, sc[mf], 0, 0, 0);
    }
    // e = exp(s) (no max needed: |s| <= 8), rowsum partials, stash e in LDS
    for (int mf = 0; mf < 2; mf++)
      for (int r = 0; r < 4; r++) {
        float e = __expf(sc[mf][r]);
        rs[mf][r] += e;
        int i = 16 * mf + 4 * lq + r;
        int jl = 16 * w + l15;
        int byte = (i * 128 + jl * 2) ^ ((i & 7) << 4);
        *(unsigned short*)((char*)e_s + byte) = f2bf(e);
      }
    __syncthreads();
    // PV: acc[i][c] += e[i][j] * vt[c][j]
    for (int ks = 0; ks < 2; ks++) {
      s16x8 ef[2];
      for (int mf = 0; mf < 2; mf++) {
        int i = 16 * mf + l15;
        int byte = (i * 128 + 64 * ks + 16 * lq) ^ ((i & 7) << 4);
        ef[mf] = *(const s16x8*)((const char*)e_s + byte);
      }
      for (int nf = 0; nf < 8; nf++) {
        s16x8 vf = *(const s16x8*)(vtb + (size_t)(128 * w + 16 * nf + l15) * NN + jb + 32 * ks + 8 * lq);
        for (int mf = 0; mf < 2; mf++)
          acc[mf][nf] = __builtin_amdgcn_mfma_f32_16x16x32_bf16(ef[mf], vf, acc[mf][nf], 0, 0, 0);
      }
    }
    __syncthreads();
  }

  // rowsum: reduce over 16-lane groups, then across waves via LDS
  for (int mf = 0; mf < 2; mf++)
    for (int r = 0; r < 4; r++) {
      float v = rs[mf][r];
      v += __shfl_xor(v, 1); v += __shfl_xor(v, 2);
      v += __shfl_xor(v, 4); v += __shfl_xor(v, 8);
      rs[mf][r] = v;
    }
  if (l15 == 0)
    for (int mf = 0; mf < 2; mf++)
      for (int r = 0; r < 4; r++)
        rs_s[w][16 * mf + 4 * lq + r] = rs[mf][r];
  __syncthreads();
  float inv[2][4];
  for (int mf = 0; mf < 2; mf++)
    for (int r = 0; r < 4; r++) {
      int i = 16 * mf + 4 * lq + r;
      inv[mf][r] = 1.0f / (rs_s[0][i] + rs_s[1][i] + rs_s[2][i] + rs_s[3][i]);
    }
  // content = px + attn@v  (content aliases px16: each element read+written by one lane)
  unsigned short* cbuf = content + ((size_t)b * NN + ib) * CC;
  for (int mf = 0; mf < 2; mf++)
    for (int nf = 0; nf < 8; nf++)
      for (int r = 0; r < 4; r++) {
        int i = 16 * mf + 4 * lq + r;
        int c = 128 * w + 16 * nf + l15;
        float v = bf2f(cbuf[(size_t)i * CC + c]) + acc[mf][nf][r] * inv[mf][r];
        cbuf[(size_t)i * CC + c] = f2bf(v);
      }
}

// ---------------- FC: out[b][c2][n] = content[b][n][:] @ Wfc[c2][:] + bfc ----------------
__global__ __launch_bounds__(256, 2) void k_fc(const unsigned short* __restrict__ content,
                                               const unsigned short* __restrict__ wfc16,
                                               const float* __restrict__ bfc,
                                               float* __restrict__ out) {
  int cb = blockIdx.x * 64;
  int fb = blockIdx.y * 256;
  int tid = threadIdx.x;
  int w = tid >> 6, l = tid & 63, l15 = l & 15, lq = l >> 4;
  int fw = fb + 64 * w;
  f32x4 acc[4][4];
  for (int mf = 0; mf < 4; mf++) for (int nf = 0; nf < 4; nf++) acc[mf][nf] = (f32x4){0.f, 0.f, 0.f, 0.f};
  for (int kk = 0; kk < 16; kk++) {
    int k0 = kk * 32 + 8 * lq;
    s16x8 a[4], bb[4];
    for (int mf = 0; mf < 4; mf++)
      a[mf] = *(const s16x8*)(wfc16 + (size_t)(cb + 16 * mf + l15) * CC + k0);
    for (int nf = 0; nf < 4; nf++)
      bb[nf] = *(const s16x8*)(content + (size_t)(fw + 16 * nf + l15) * CC + k0);
    for (int mf = 0; mf < 4; mf++)
      for (int nf = 0; nf < 4; nf++)
        acc[mf][nf] = __builtin_amdgcn_mfma_f32_16x16x32_bf16(a[mf], bb[nf], acc[mf][nf], 0, 0, 0);
  }
  for (int mf = 0; mf < 4; mf++)
    for (int nf = 0; nf < 4; nf++)
      for (int r = 0; r < 4; r++) {
        int c2 = cb + 16 * mf + 4 * lq + r;
        int flat = fw + 16 * nf + l15;
        int b2 = flat / NN;
        int n = flat - b2 * NN;
        out[((size_t)b2 * CC + c2) * NN + n] = acc[mf][nf][r] + bfc[c2];
      }
}

// ---------------- BN stats per channel ----------------
__global__ void k_stats(const float* __restrict__ out, const float* __restrict__ gamma,
                        const float* __restrict__ beta, float2* __restrict__ ab) {
  int c = blockIdx.x;
  int tid = threadIdx.x;
  float s = 0.f, sq = 0.f;
  for (int idx = tid; idx < BB * NN; idx += 256) {
    int b2 = idx / NN, n = idx - b2 * NN;
    float v = out[((size_t)b2 * CC + c) * NN + n];
    s += v; sq += v * v;
  }
  for (int m = 1; m <= 32; m <<= 1) { s += __shfl_xor(s, m); sq += __shfl_xor(sq, m); }
  __shared__ float ss[4], ssq[4];
  int w = tid >> 6;
  if ((tid & 63) == 0) { ss[w] = s; ssq[w] = sq; }
  __syncthreads();
  if (tid == 0) {
    float S = ss[0] + ss[1] + ss[2] + ss[3];
    float SQ = ssq[0] + ssq[1] + ssq[2] + ssq[3];
    const float invn = 1.0f / (BB * NN);
    float mean = S * invn;
    float var = SQ * invn - mean * mean;
    float a = gamma[c] * rsqrtf(var + 1e-5f);
    ab[c] = make_float2(a, beta[c] - mean * a);
  }
}

// ---------------- BN apply + ReLU, in-place on out ----------------
__global__ void k_bn(float* __restrict__ out, const float2* __restrict__ ab) {
  int idx = blockIdx.x * 256 + threadIdx.x;  // float4 index
  const int total = BB * CC * NN / 4;
  if (idx >= total) return;
  int c = (idx / (NN / 4)) & (CC - 1);
  float2 p = ab[c];
  f32x4 v = ((f32x4*)out)[idx];
  for (int i = 0; i < 4; i++) v[i] = fmaxf(0.f, v[i] * p.x + p.y);
  ((f32x4*)out)[idx] = v;
}

extern "C" void kernel_launch(void* const* d_in, const int* in_sizes, int n_in,
                              void* d_out, int out_size, void* d_ws, size_t ws_size,
                              hipStream_t stream) {
  const float* x = (const float*)d_in[0];
  const float* Wq = (const float*)d_in[1];
  const float* Wk = (const float*)d_in[2];
  const float* Wv = (const float*)d_in[3];
  const float* align_w = (const float*)d_in[4];
  const float* Wfc = (const float*)d_in[5];
  const float* bfc = (const float*)d_in[6];
  const float* gamma = (const float*)d_in[7];
  const float* beta = (const float*)d_in[8];
  float* out = (float*)d_out;

  char* ws = (char*)d_ws;
  const size_t sz_px = (size_t)BB * NN * CC * 2;   // 18,874,368 (also content, aliased)
  const size_t sz_qkv = (size_t)BB * NN * 640 * 2; // 23,592,960
  const size_t sz_vt = (size_t)BB * CC * NN * 2;   // 18,874,368
  unsigned short* px16 = (unsigned short*)(ws);
  unsigned short* qkv = (unsigned short*)(ws + sz_px);
  unsigned short* vt = (unsigned short*)(ws + sz_px + sz_qkv);
  unsigned short* wcat = (unsigned short*)(ws + sz_px + sz_qkv + sz_vt);
  unsigned short* wfc16 = (unsigned short*)(ws + sz_px + sz_qkv + sz_vt + 640 * 512 * 2);
  float2* ab = (float2*)(ws + sz_px + sz_qkv + sz_vt + 640 * 512 * 2 + 512 * 512 * 2);

  k_prep_w<<<(640 * 512 + 512 * 512 + 255) / 256, 256, 0, stream>>>(Wq, Wk, Wv, Wfc, wcat, wfc16);
  k_px<<<dim3(BB, NN / 32, CC / 32), 256, 0, stream>>>(x, px16);
  k_qkv<<<dim3(BB, NN / 64, 5), 256, 0, stream>>>(px16, wcat, align_w, qkv);
  k_vt<<<dim3(BB, NN / 32, CC / 32), 256, 0, stream>>>(qkv, vt);
  k_attn<<<dim3(BB, NN / 32), 256, 0, stream>>>(qkv, vt, px16 /* content in-place */);
  k_fc<<<dim3(CC / 64, BB * NN / 256), 256, 0, stream>>>(px16, wfc16, bfc, out);
  k_stats<<<CC, 256, 0, stream>>>(out, gamma, beta, ab);
  k_bn<<<(BB * CC * NN / 4 + 255) / 256, 256, 0, stream>>>(out, ab);
}

// Round 2
// 393.038 us; speedup vs baseline: 1.0356x; 1.0356x over previous
//
#include <hip/hip_runtime.h>
#include <stdint.h>

#define BB 8
#define CC 512
#define NN 2304
#define PP 64

typedef float f32x4 __attribute__((ext_vector_type(4)));
typedef short s16x8 __attribute__((ext_vector_type(8)));

__device__ __forceinline__ unsigned short f2bf(float f) {
  union { float f; uint32_t u; } v; v.f = f;
  uint32_t u = v.u;
  return (unsigned short)((u + 0x7FFFu + ((u >> 16) & 1u)) >> 16);
}
__device__ __forceinline__ float bf2f(unsigned short b) {
  union { uint32_t u; float f; } v; v.u = ((uint32_t)b) << 16;
  return v.f;
}

// ---------------- prep: bf16 weight concat [Wq|Wk|Wv] rows + Wfc ----------------
__global__ void k_prep_w(const float* __restrict__ Wq, const float* __restrict__ Wk,
                         const float* __restrict__ Wv, const float* __restrict__ Wfc,
                         unsigned short* __restrict__ wcat, unsigned short* __restrict__ wfc16) {
  int idx = blockIdx.x * 256 + threadIdx.x;
  const int tot_cat = 640 * 512;
  const int total = tot_cat + 512 * 512;
  if (idx >= total) return;
  if (idx < tot_cat) {
    int j = idx >> 9, k = idx & 511;
    float v = (j < 64) ? Wq[j * 512 + k] : ((j < 128) ? Wk[(j - 64) * 512 + k] : Wv[(j - 128) * 512 + k]);
    wcat[idx] = f2bf(v);
  } else {
    int i2 = idx - tot_cat;
    wfc16[i2] = f2bf(Wfc[i2]);
  }
}

// ---------------- px16[b][n][c] = bf16(x[b][c][n]) ----------------
__global__ void k_px(const float* __restrict__ x, unsigned short* __restrict__ px16) {
  __shared__ float t[32][33];
  int b = blockIdx.x;
  int nb = blockIdx.y * 32;
  int cb = blockIdx.z * 32;
  int lane = threadIdx.x & 31;
  int row = threadIdx.x >> 5;  // 0..7
  const float* xb = x + (size_t)b * CC * NN;
  for (int rr = 0; rr < 4; rr++) {
    int c = cb + row + 8 * rr;
    t[row + 8 * rr][lane] = xb[(size_t)c * NN + nb + lane];
  }
  __syncthreads();
  unsigned short* pb = px16 + (size_t)b * NN * CC;
  for (int rr = 0; rr < 4; rr++) {
    int n = nb + row + 8 * rr;
    pb[(size_t)n * CC + cb + lane] = f2bf(t[lane][row + 8 * rr]);
  }
}

// ---------------- QKV GEMM: qkv[b][n][j], j<64: tanh*align_w, j<128: tanh, else v ----------------
__global__ __launch_bounds__(256, 2) void k_qkv(const unsigned short* __restrict__ px16,
                                                const unsigned short* __restrict__ wcat,
                                                const float* __restrict__ align_w,
                                                unsigned short* __restrict__ qkv) {
  int b = blockIdx.x;
  int nb = blockIdx.y * 64;
  int jb0 = blockIdx.z * 128;
  int tid = threadIdx.x;
  int w = tid >> 6, l = tid & 63, l15 = l & 15, lq = l >> 4;
  int jw = jb0 + 32 * w;
  const unsigned short* A = px16 + ((size_t)b * NN + nb) * CC;  // [64][512]
  f32x4 acc[4][2];
  for (int mf = 0; mf < 4; mf++) for (int nf = 0; nf < 2; nf++) acc[mf][nf] = (f32x4){0.f, 0.f, 0.f, 0.f};
  for (int kk = 0; kk < 16; kk++) {
    int k0 = kk * 32 + 8 * lq;
    s16x8 a[4], bb[2];
    for (int mf = 0; mf < 4; mf++)
      a[mf] = *(const s16x8*)(A + (size_t)(16 * mf + l15) * CC + k0);
    for (int nf = 0; nf < 2; nf++)
      bb[nf] = *(const s16x8*)(wcat + (size_t)(jw + 16 * nf + l15) * CC + k0);
    for (int mf = 0; mf < 4; mf++)
      for (int nf = 0; nf < 2; nf++)
        acc[mf][nf] = __builtin_amdgcn_mfma_f32_16x16x32_bf16(a[mf], bb[nf], acc[mf][nf], 0, 0, 0);
  }
  unsigned short* O = qkv + ((size_t)b * NN + nb) * 640;
  for (int mf = 0; mf < 4; mf++)
    for (int nf = 0; nf < 2; nf++)
      for (int r = 0; r < 4; r++) {
        int n = 16 * mf + 4 * lq + r;
        int j = jw + 16 * nf + l15;
        float v = acc[mf][nf][r];
        if (j < 128) { v = tanhf(v); if (j < 64) v *= align_w[j]; }
        O[(size_t)n * 640 + j] = f2bf(v);
      }
}

// ---------------- vt16[b][c][n] = v part of qkv (transpose) ----------------
__global__ void k_vt(const unsigned short* __restrict__ qkv, unsigned short* __restrict__ vt) {
  __shared__ uint32_t t[32][33];
  int b = blockIdx.x;
  int nb = blockIdx.y * 32;
  int cb = blockIdx.z * 32;
  int lane = threadIdx.x & 31;
  int row = threadIdx.x >> 5;
  const unsigned short* src = qkv + (size_t)b * NN * 640 + 128;
  for (int rr = 0; rr < 4; rr++) {
    int n = nb + row + 8 * rr;
    t[row + 8 * rr][lane] = (uint32_t)src[(size_t)n * 640 + cb + lane];
  }
  __syncthreads();
  unsigned short* dst = vt + (size_t)b * CC * NN;
  for (int rr = 0; rr < 4; rr++) {
    int c = cb + row + 8 * rr;
    dst[(size_t)c * NN + nb + lane] = (unsigned short)t[lane][row + 8 * rr];
  }
}

// ---------------- fused attention: content[b][n][ch..ch+256] = px + softmax(qa k^T) v ----------------
// i-tile = 32 rows, c-split x2 across blockIdx.z. 4 waves: scores j-slice 16/wave,
// PV c-slice 64/wave. K then V fragment loads hoisted to top of each jt iteration so
// V latency hides under scores+exp+LDS+barrier (vmcnt drains in order).
__global__ __launch_bounds__(256, 4) void k_attn(const unsigned short* __restrict__ qkv,
                                                 const unsigned short* __restrict__ vt,
                                                 unsigned short* __restrict__ content /* aliases px16 */) {
  __shared__ __align__(16) unsigned short e_s[32 * 64];  // XOR-swizzled
  __shared__ float rs_s[4][32];
  int b = blockIdx.x;
  int ib = blockIdx.y * 32;
  int ch = blockIdx.z * 256;  // channel half
  int tid = threadIdx.x;
  int w = tid >> 6, l = tid & 63, l15 = l & 15, lq = l >> 4;
  const unsigned short* qkvb = qkv + (size_t)b * NN * 640;
  const unsigned short* kbase = qkvb + 64;
  const unsigned short* vtb = vt + (size_t)b * CC * NN;

  s16x8 qa[2][2];
  for (int mf = 0; mf < 2; mf++)
    for (int ks = 0; ks < 2; ks++)
      qa[mf][ks] = *(const s16x8*)(qkvb + (size_t)(ib + 16 * mf + l15) * 640 + 32 * ks + 8 * lq);

  f32x4 acc[2][4];
  for (int mf = 0; mf < 2; mf++) for (int nf = 0; nf < 4; nf++) acc[mf][nf] = (f32x4){0.f, 0.f, 0.f, 0.f};
  float rs[2][4];
  for (int mf = 0; mf < 2; mf++) for (int r = 0; r < 4; r++) rs[mf][r] = 0.f;

  for (int jt = 0; jt < NN / 64; jt++) {
    int jb = jt * 64;
    // ---- issue K loads first, then V loads (vmcnt drains in order: score MFMAs
    // only wait for K; the 8 V loads stay in flight until PV) ----
    s16x8 kf[2];
    for (int ks = 0; ks < 2; ks++)
      kf[ks] = *(const s16x8*)(kbase + (size_t)(jb + 16 * w + l15) * 640 + 32 * ks + 8 * lq);
    s16x8 vf[2][4];
    for (int ks = 0; ks < 2; ks++)
      for (int nf = 0; nf < 4; nf++)
        vf[ks][nf] = *(const s16x8*)(vtb + (size_t)(ch + 64 * w + 16 * nf + l15) * NN + jb + 32 * ks + 8 * lq);
    // scores for wave's 16-j slice
    f32x4 sc[2];
    sc[0] = (f32x4){0.f, 0.f, 0.f, 0.f};
    sc[1] = (f32x4){0.f, 0.f, 0.f, 0.f};
    for (int ks = 0; ks < 2; ks++)
      for (int mf = 0; mf < 2; mf++)
        sc[mf] = __builtin_amdgcn_mfma_f32_16x16x32_bf16(qa[mf][ks], kf[ks], sc[mf], 0, 0, 0);
    // e = exp(s) (no max needed: |s| <= 8), rowsum partials, stash e in LDS
    for (int mf = 0; mf < 2; mf++)
      for (int r = 0; r < 4; r++) {
        float e = __expf(sc[mf][r]);
        rs[mf][r] += e;
        int i = 16 * mf + 4 * lq + r;
        int jl = 16 * w + l15;
        int byte = (i * 128 + jl * 2) ^ ((i & 7) << 4);
        *(unsigned short*)((char*)e_s + byte) = f2bf(e);
      }
    __syncthreads();
    // PV: acc[i][c] += e[i][j] * vt[c][j]
    for (int ks = 0; ks < 2; ks++) {
      s16x8 ef[2];
      for (int mf = 0; mf < 2; mf++) {
        int i = 16 * mf + l15;
        int byte = (i * 128 + 64 * ks + 16 * lq) ^ ((i & 7) << 4);
        ef[mf] = *(const s16x8*)((const char*)e_s + byte);
      }
      for (int nf = 0; nf < 4; nf++)
        for (int mf = 0; mf < 2; mf++)
          acc[mf][nf] = __builtin_amdgcn_mfma_f32_16x16x32_bf16(ef[mf], vf[ks][nf], acc[mf][nf], 0, 0, 0);
    }
    __syncthreads();
  }

  // rowsum: reduce over 16-lane groups, then across waves via LDS
  for (int mf = 0; mf < 2; mf++)
    for (int r = 0; r < 4; r++) {
      float v = rs[mf][r];
      v += __shfl_xor(v, 1); v += __shfl_xor(v, 2);
      v += __shfl_xor(v, 4); v += __shfl_xor(v, 8);
      rs[mf][r] = v;
    }
  if (l15 == 0)
    for (int mf = 0; mf < 2; mf++)
      for (int r = 0; r < 4; r++)
        rs_s[w][16 * mf + 4 * lq + r] = rs[mf][r];
  __syncthreads();
  float inv[2][4];
  for (int mf = 0; mf < 2; mf++)
    for (int r = 0; r < 4; r++) {
      int i = 16 * mf + 4 * lq + r;
      inv[mf][r] = 1.0f / (rs_s[0][i] + rs_s[1][i] + rs_s[2][i] + rs_s[3][i]);
    }
  // content = px + attn@v  (content aliases px16: each element read+written by one lane)
  unsigned short* cbuf = content + ((size_t)b * NN + ib) * CC;
  for (int mf = 0; mf < 2; mf++)
    for (int nf = 0; nf < 4; nf++)
      for (int r = 0; r < 4; r++) {
        int i = 16 * mf + 4 * lq + r;
        int c = ch + 64 * w + 16 * nf + l15;
        float v = bf2f(cbuf[(size_t)i * CC + c]) + acc[mf][nf][r] * inv[mf][r];
        cbuf[(size_t)i * CC + c] = f2bf(v);
      }
}

// ---------------- FC: out[b][c2][n] = content[b][n][:] @ Wfc[c2][:] + bfc ----------------
__global__ __launch_bounds__(256, 2) void k_fc(const unsigned short* __restrict__ content,
                                               const unsigned short* __restrict__ wfc16,
                                               const float* __restrict__ bfc,
                                               float* __restrict__ out) {
  int cb = blockIdx.x * 64;
  int fb = blockIdx.y * 256;
  int tid = threadIdx.x;
  int w = tid >> 6, l = tid & 63, l15 = l & 15, lq = l >> 4;
  int fw = fb + 64 * w;
  f32x4 acc[4][4];
  for (int mf = 0; mf < 4; mf++) for (int nf = 0; nf < 4; nf++) acc[mf][nf] = (f32x4){0.f, 0.f, 0.f, 0.f};
  for (int kk = 0; kk < 16; kk++) {
    int k0 = kk * 32 + 8 * lq;
    s16x8 a[4], bb[4];
    for (int mf = 0; mf < 4; mf++)
      a[mf] = *(const s16x8*)(wfc16 + (size_t)(cb + 16 * mf + l15) * CC + k0);
    for (int nf = 0; nf < 4; nf++)
      bb[nf] = *(const s16x8*)(content + (size_t)(fw + 16 * nf + l15) * CC + k0);
    for (int mf = 0; mf < 4; mf++)
      for (int nf = 0; nf < 4; nf++)
        acc[mf][nf] = __builtin_amdgcn_mfma_f32_16x16x32_bf16(a[mf], bb[nf], acc[mf][nf], 0, 0, 0);
  }
  for (int mf = 0; mf < 4; mf++)
    for (int nf = 0; nf < 4; nf++)
      for (int r = 0; r < 4; r++) {
        int c2 = cb + 16 * mf + 4 * lq + r;
        int flat = fw + 16 * nf + l15;
        int b2 = flat / NN;
        int n = flat - b2 * NN;
        out[((size_t)b2 * CC + c2) * NN + n] = acc[mf][nf][r] + bfc[c2];
      }
}

// ---------------- BN stats per channel ----------------
__global__ void k_stats(const float* __restrict__ out, const float* __restrict__ gamma,
                        const float* __restrict__ beta, float2* __restrict__ ab) {
  int c = blockIdx.x;
  int tid = threadIdx.x;
  float s = 0.f, sq = 0.f;
  for (int idx = tid; idx < BB * NN; idx += 256) {
    int b2 = idx / NN, n = idx - b2 * NN;
    float v = out[((size_t)b2 * CC + c) * NN + n];
    s += v; sq += v * v;
  }
  for (int m = 1; m <= 32; m <<= 1) { s += __shfl_xor(s, m); sq += __shfl_xor(sq, m); }
  __shared__ float ss[4], ssq[4];
  int w = tid >> 6;
  if ((tid & 63) == 0) { ss[w] = s; ssq[w] = sq; }
  __syncthreads();
  if (tid == 0) {
    float S = ss[0] + ss[1] + ss[2] + ss[3];
    float SQ = ssq[0] + ssq[1] + ssq[2] + ssq[3];
    const float invn = 1.0f / (BB * NN);
    float mean = S * invn;
    float var = SQ * invn - mean * mean;
    float a = gamma[c] * rsqrtf(var + 1e-5f);
    ab[c] = make_float2(a, beta[c] - mean * a);
  }
}

// ---------------- BN apply + ReLU, in-place on out ----------------
__global__ void k_bn(float* __restrict__ out, const float2* __restrict__ ab) {
  int idx = blockIdx.x * 256 + threadIdx.x;  // float4 index
  const int total = BB * CC * NN / 4;
  if (idx >= total) return;
  int c = (idx / (NN / 4)) & (CC - 1);
  float2 p = ab[c];
  f32x4 v = ((f32x4*)out)[idx];
  for (int i = 0; i < 4; i++) v[i] = fmaxf(0.f, v[i] * p.x + p.y);
  ((f32x4*)out)[idx] = v;
}

extern "C" void kernel_launch(void* const* d_in, const int* in_sizes, int n_in,
                              void* d_out, int out_size, void* d_ws, size_t ws_size,
                              hipStream_t stream) {
  const float* x = (const float*)d_in[0];
  const float* Wq = (const float*)d_in[1];
  const float* Wk = (const float*)d_in[2];
  const float* Wv = (const float*)d_in[3];
  const float* align_w = (const float*)d_in[4];
  const float* Wfc = (const float*)d_in[5];
  const float* bfc = (const float*)d_in[6];
  const float* gamma = (const float*)d_in[7];
  const float* beta = (const float*)d_in[8];
  float* out = (float*)d_out;

  char* ws = (char*)d_ws;
  const size_t sz_px = (size_t)BB * NN * CC * 2;   // 18,874,368 (also content, aliased)
  const size_t sz_qkv = (size_t)BB * NN * 640 * 2; // 23,592,960
  const size_t sz_vt = (size_t)BB * CC * NN * 2;   // 18,874,368
  unsigned short* px16 = (unsigned short*)(ws);
  unsigned short* qkv = (unsigned short*)(ws + sz_px);
  unsigned short* vt = (unsigned short*)(ws + sz_px + sz_qkv);
  unsigned short* wcat = (unsigned short*)(ws + sz_px + sz_qkv + sz_vt);
  unsigned short* wfc16 = (unsigned short*)(ws + sz_px + sz_qkv + sz_vt + 640 * 512 * 2);
  float2* ab = (float2*)(ws + sz_px + sz_qkv + sz_vt + 640 * 512 * 2 + 512 * 512 * 2);

  k_prep_w<<<(640 * 512 + 512 * 512 + 255) / 256, 256, 0, stream>>>(Wq, Wk, Wv, Wfc, wcat, wfc16);
  k_px<<<dim3(BB, NN / 32, CC / 32), 256, 0, stream>>>(x, px16);
  k_qkv<<<dim3(BB, NN / 64, 5), 256, 0, stream>>>(px16, wcat, align_w, qkv);
  k_vt<<<dim3(BB, NN / 32, CC / 32), 256, 0, stream>>>(qkv, vt);
  k_attn<<<dim3(BB, NN / 32, 2), 256, 0, stream>>>(qkv, vt, px16 /* content in-place */);
  k_fc<<<dim3(CC / 64, BB * NN / 256), 256, 0, stream>>>(px16, wfc16, bfc, out);
  k_stats<<<CC, 256, 0, stream>>>(out, gamma, beta, ab);
  k_bn<<<(BB * CC * NN / 4 + 255) / 256, 256, 0, stream>>>(out, ab);
}

// Round 3
// 390.658 us; speedup vs baseline: 1.0419x; 1.0061x over previous
//
#include <hip/hip_runtime.h>
#include <stdint.h>

#define BB 8
#define CC 512
#define NN 2304
#define PP 64

typedef float f32x4 __attribute__((ext_vector_type(4)));
typedef short s16x8 __attribute__((ext_vector_type(8)));

__device__ __forceinline__ unsigned short f2bf(float f) {
  union { float f; uint32_t u; } v; v.f = f;
  uint32_t u = v.u;
  return (unsigned short)((u + 0x7FFFu + ((u >> 16) & 1u)) >> 16);
}
__device__ __forceinline__ float bf2f(unsigned short b) {
  union { uint32_t u; float f; } v; v.u = ((uint32_t)b) << 16;
  return v.f;
}

// ---------------- prep: bf16 weight concat [Wq|Wk|Wv] rows + Wfc ----------------
__global__ void k_prep_w(const float* __restrict__ Wq, const float* __restrict__ Wk,
                         const float* __restrict__ Wv, const float* __restrict__ Wfc,
                         unsigned short* __restrict__ wcat, unsigned short* __restrict__ wfc16) {
  int idx = blockIdx.x * 256 + threadIdx.x;
  const int tot_cat = 640 * 512;
  const int total = tot_cat + 512 * 512;
  if (idx >= total) return;
  if (idx < tot_cat) {
    int j = idx >> 9, k = idx & 511;
    float v = (j < 64) ? Wq[j * 512 + k] : ((j < 128) ? Wk[(j - 64) * 512 + k] : Wv[(j - 128) * 512 + k]);
    wcat[idx] = f2bf(v);
  } else {
    int i2 = idx - tot_cat;
    wfc16[i2] = f2bf(Wfc[i2]);
  }
}

// ---------------- px16[b][n][c] = bf16(x[b][c][n]) ----------------
__global__ void k_px(const float* __restrict__ x, unsigned short* __restrict__ px16) {
  __shared__ float t[32][33];
  int b = blockIdx.x;
  int nb = blockIdx.y * 32;
  int cb = blockIdx.z * 32;
  int lane = threadIdx.x & 31;
  int row = threadIdx.x >> 5;  // 0..7
  const float* xb = x + (size_t)b * CC * NN;
  for (int rr = 0; rr < 4; rr++) {
    int c = cb + row + 8 * rr;
    t[row + 8 * rr][lane] = xb[(size_t)c * NN + nb + lane];
  }
  __syncthreads();
  unsigned short* pb = px16 + (size_t)b * NN * CC;
  for (int rr = 0; rr < 4; rr++) {
    int n = nb + row + 8 * rr;
    pb[(size_t)n * CC + cb + lane] = f2bf(t[lane][row + 8 * rr]);
  }
}

// ---------------- QKV GEMM: qkv[b][n][j], j<64: tanh*align_w, j<128: tanh, else v ----------------
__global__ __launch_bounds__(256, 2) void k_qkv(const unsigned short* __restrict__ px16,
                                                const unsigned short* __restrict__ wcat,
                                                const float* __restrict__ align_w,
                                                unsigned short* __restrict__ qkv) {
  int b = blockIdx.x;
  int nb = blockIdx.y * 64;
  int jb0 = blockIdx.z * 128;
  int tid = threadIdx.x;
  int w = tid >> 6, l = tid & 63, l15 = l & 15, lq = l >> 4;
  int jw = jb0 + 32 * w;
  const unsigned short* A = px16 + ((size_t)b * NN + nb) * CC;  // [64][512]
  f32x4 acc[4][2];
  for (int mf = 0; mf < 4; mf++) for (int nf = 0; nf < 2; nf++) acc[mf][nf] = (f32x4){0.f, 0.f, 0.f, 0.f};
  for (int kk = 0; kk < 16; kk++) {
    int k0 = kk * 32 + 8 * lq;
    s16x8 a[4], bb[2];
    for (int mf = 0; mf < 4; mf++)
      a[mf] = *(const s16x8*)(A + (size_t)(16 * mf + l15) * CC + k0);
    for (int nf = 0; nf < 2; nf++)
      bb[nf] = *(const s16x8*)(wcat + (size_t)(jw + 16 * nf + l15) * CC + k0);
    for (int mf = 0; mf < 4; mf++)
      for (int nf = 0; nf < 2; nf++)
        acc[mf][nf] = __builtin_amdgcn_mfma_f32_16x16x32_bf16(a[mf], bb[nf], acc[mf][nf], 0, 0, 0);
  }
  unsigned short* O = qkv + ((size_t)b * NN + nb) * 640;
  for (int mf = 0; mf < 4; mf++)
    for (int nf = 0; nf < 2; nf++)
      for (int r = 0; r < 4; r++) {
        int n = 16 * mf + 4 * lq + r;
        int j = jw + 16 * nf + l15;
        float v = acc[mf][nf][r];
        if (j < 128) { v = tanhf(v); if (j < 64) v *= align_w[j]; }
        O[(size_t)n * 640 + j] = f2bf(v);
      }
}

// ---------------- vt16[b][c][n] = v part of qkv (transpose) ----------------
__global__ void k_vt(const unsigned short* __restrict__ qkv, unsigned short* __restrict__ vt) {
  __shared__ uint32_t t[32][33];
  int b = blockIdx.x;
  int nb = blockIdx.y * 32;
  int cb = blockIdx.z * 32;
  int lane = threadIdx.x & 31;
  int row = threadIdx.x >> 5;
  const unsigned short* src = qkv + (size_t)b * NN * 640 + 128;
  for (int rr = 0; rr < 4; rr++) {
    int n = nb + row + 8 * rr;
    t[row + 8 * rr][lane] = (uint32_t)src[(size_t)n * 640 + cb + lane];
  }
  __syncthreads();
  unsigned short* dst = vt + (size_t)b * CC * NN;
  for (int rr = 0; rr < 4; rr++) {
    int c = cb + row + 8 * rr;
    dst[(size_t)c * NN + nb + lane] = (unsigned short)t[lane][row + 8 * rr];
  }
}

// ---------------- fused attention: content[b][n][ch..ch+256] = px + softmax(qa k^T) v ----------------
// i-tile = 32 rows, c-split x2 across blockIdx.z. 4 waves: scores j-slice 16/wave,
// PV c-slice 64/wave.
// Pipeline (R3): raw s_barrier + explicit lgkmcnt(0) only (NO vmcnt drain), double-buffered
// e_s -> ONE barrier per jt iteration. V(t) issued at top of iteration t (covered by
// scores+exp+barrier); K(t+1) register-prefetched one iteration ahead (fully covered).
__global__ __launch_bounds__(256, 2) void k_attn(const unsigned short* __restrict__ qkv,
                                                 const unsigned short* __restrict__ vt,
                                                 unsigned short* __restrict__ content /* aliases px16 */) {
  __shared__ __align__(16) unsigned short e_s[2][32 * 64];  // XOR-swizzled, double-buffered
  __shared__ float rs_s[4][32];
  int b = blockIdx.x;
  int ib = blockIdx.y * 32;
  int ch = blockIdx.z * 256;  // channel half
  int tid = threadIdx.x;
  int w = tid >> 6, l = tid & 63, l15 = l & 15, lq = l >> 4;
  const unsigned short* qkvb = qkv + (size_t)b * NN * 640;
  const unsigned short* kbase = qkvb + 64;
  const unsigned short* vtb = vt + (size_t)b * CC * NN;

  s16x8 qa[2][2];
  for (int mf = 0; mf < 2; mf++)
    for (int ks = 0; ks < 2; ks++)
      qa[mf][ks] = *(const s16x8*)(qkvb + (size_t)(ib + 16 * mf + l15) * 640 + 32 * ks + 8 * lq);

  f32x4 acc[2][4];
  for (int mf = 0; mf < 2; mf++) for (int nf = 0; nf < 4; nf++) acc[mf][nf] = (f32x4){0.f, 0.f, 0.f, 0.f};
  float rs[2][4];
  for (int mf = 0; mf < 2; mf++) for (int r = 0; r < 4; r++) rs[mf][r] = 0.f;

  // prologue: K(0)
  s16x8 kf[2];
  for (int ks = 0; ks < 2; ks++)
    kf[ks] = *(const s16x8*)(kbase + (size_t)(16 * w + l15) * 640 + 32 * ks + 8 * lq);

  for (int jt = 0; jt < NN / 64; jt++) {
    int jb = jt * 64;
    int jb_n = (jt < NN / 64 - 1) ? jb + 64 : jb;
    // ---- issue V(t) loads (used after the barrier; never force-drained) ----
    s16x8 vf[2][4];
    for (int ks = 0; ks < 2; ks++)
      for (int nf = 0; nf < 4; nf++)
        vf[ks][nf] = *(const s16x8*)(vtb + (size_t)(ch + 64 * w + 16 * nf + l15) * NN + jb + 32 * ks + 8 * lq);
    // ---- issue K(t+1) prefetch ----
    s16x8 kn[2];
    for (int ks = 0; ks < 2; ks++)
      kn[ks] = *(const s16x8*)(kbase + (size_t)(jb_n + 16 * w + l15) * 640 + 32 * ks + 8 * lq);
    // ---- scores for wave's 16-j slice, using K(t) loaded last iteration ----
    f32x4 sc[2];
    sc[0] = (f32x4){0.f, 0.f, 0.f, 0.f};
    sc[1] = (f32x4){0.f, 0.f, 0.f, 0.f};
    for (int ks = 0; ks < 2; ks++)
      for (int mf = 0; mf < 2; mf++)
        sc[mf] = __builtin_amdgcn_mfma_f32_16x16x32_bf16(qa[mf][ks], kf[ks], sc[mf], 0, 0, 0);
    // ---- e = exp(s) (|s| <= 8, no max needed), rowsum partials, stash in e_s[t&1] ----
    char* ebuf = (char*)e_s[jt & 1];
    for (int mf = 0; mf < 2; mf++)
      for (int r = 0; r < 4; r++) {
        float e = __expf(sc[mf][r]);
        rs[mf][r] += e;
        int i = 16 * mf + 4 * lq + r;
        int jl = 16 * w + l15;
        int byte = (i * 128 + jl * 2) ^ ((i & 7) << 4);
        *(unsigned short*)(ebuf + byte) = f2bf(e);
      }
    // ---- raw barrier: drain only LDS (ds_write visibility), keep global loads in flight ----
    asm volatile("s_waitcnt lgkmcnt(0)" ::: "memory");
    __builtin_amdgcn_s_barrier();
    __builtin_amdgcn_sched_barrier(0);
    // ---- PV: acc[i][c] += e[i][j] * vt[c][j] ----
    for (int ks = 0; ks < 2; ks++) {
      s16x8 ef[2];
      for (int mf = 0; mf < 2; mf++) {
        int i = 16 * mf + l15;
        int byte = (i * 128 + 64 * ks + 16 * lq) ^ ((i & 7) << 4);
        ef[mf] = *(const s16x8*)(ebuf + byte);
      }
      for (int nf = 0; nf < 4; nf++)
        for (int mf = 0; mf < 2; mf++)
          acc[mf][nf] = __builtin_amdgcn_mfma_f32_16x16x32_bf16(ef[mf], vf[ks][nf], acc[mf][nf], 0, 0, 0);
    }
    // no second barrier: next iteration writes the OTHER e_s buffer
    kf[0] = kn[0];
    kf[1] = kn[1];
  }

  // rowsum: reduce over 16-lane groups, then across waves via LDS
  for (int mf = 0; mf < 2; mf++)
    for (int r = 0; r < 4; r++) {
      float v = rs[mf][r];
      v += __shfl_xor(v, 1); v += __shfl_xor(v, 2);
      v += __shfl_xor(v, 4); v += __shfl_xor(v, 8);
      rs[mf][r] = v;
    }
  if (l15 == 0)
    for (int mf = 0; mf < 2; mf++)
      for (int r = 0; r < 4; r++)
        rs_s[w][16 * mf + 4 * lq + r] = rs[mf][r];
  __syncthreads();
  float inv[2][4];
  for (int mf = 0; mf < 2; mf++)
    for (int r = 0; r < 4; r++) {
      int i = 16 * mf + 4 * lq + r;
      inv[mf][r] = 1.0f / (rs_s[0][i] + rs_s[1][i] + rs_s[2][i] + rs_s[3][i]);
    }
  // content = px + attn@v  (content aliases px16: each element read+written by one lane)
  unsigned short* cbuf = content + ((size_t)b * NN + ib) * CC;
  for (int mf = 0; mf < 2; mf++)
    for (int nf = 0; nf < 4; nf++)
      for (int r = 0; r < 4; r++) {
        int i = 16 * mf + 4 * lq + r;
        int c = ch + 64 * w + 16 * nf + l15;
        float v = bf2f(cbuf[(size_t)i * CC + c]) + acc[mf][nf][r] * inv[mf][r];
        cbuf[(size_t)i * CC + c] = f2bf(v);
      }
}

// ---------------- FC: out[b][c2][n] = content[b][n][:] @ Wfc[c2][:] + bfc ----------------
__global__ __launch_bounds__(256, 2) void k_fc(const unsigned short* __restrict__ content,
                                               const unsigned short* __restrict__ wfc16,
                                               const float* __restrict__ bfc,
                                               float* __restrict__ out) {
  int cb = blockIdx.x * 64;
  int fb = blockIdx.y * 256;
  int tid = threadIdx.x;
  int w = tid >> 6, l = tid & 63, l15 = l & 15, lq = l >> 4;
  int fw = fb + 64 * w;
  f32x4 acc[4][4];
  for (int mf = 0; mf < 4; mf++) for (int nf = 0; nf < 4; nf++) acc[mf][nf] = (f32x4){0.f, 0.f, 0.f, 0.f};
  for (int kk = 0; kk < 16; kk++) {
    int k0 = kk * 32 + 8 * lq;
    s16x8 a[4], bb[4];
    for (int mf = 0; mf < 4; mf++)
      a[mf] = *(const s16x8*)(wfc16 + (size_t)(cb + 16 * mf + l15) * CC + k0);
    for (int nf = 0; nf < 4; nf++)
      bb[nf] = *(const s16x8*)(content + (size_t)(fw + 16 * nf + l15) * CC + k0);
    for (int mf = 0; mf < 4; mf++)
      for (int nf = 0; nf < 4; nf++)
        acc[mf][nf] = __builtin_amdgcn_mfma_f32_16x16x32_bf16(a[mf], bb[nf], acc[mf][nf], 0, 0, 0);
  }
  for (int mf = 0; mf < 4; mf++)
    for (int nf = 0; nf < 4; nf++)
      for (int r = 0; r < 4; r++) {
        int c2 = cb + 16 * mf + 4 * lq + r;
        int flat = fw + 16 * nf + l15;
        int b2 = flat / NN;
        int n = flat - b2 * NN;
        out[((size_t)b2 * CC + c2) * NN + n] = acc[mf][nf][r] + bfc[c2];
      }
}

// ---------------- BN stats per channel ----------------
__global__ void k_stats(const float* __restrict__ out, const float* __restrict__ gamma,
                        const float* __restrict__ beta, float2* __restrict__ ab) {
  int c = blockIdx.x;
  int tid = threadIdx.x;
  float s = 0.f, sq = 0.f;
  for (int idx = tid; idx < BB * NN; idx += 256) {
    int b2 = idx / NN, n = idx - b2 * NN;
    float v = out[((size_t)b2 * CC + c) * NN + n];
    s += v; sq += v * v;
  }
  for (int m = 1; m <= 32; m <<= 1) { s += __shfl_xor(s, m); sq += __shfl_xor(sq, m); }
  __shared__ float ss[4], ssq[4];
  int w = tid >> 6;
  if ((tid & 63) == 0) { ss[w] = s; ssq[w] = sq; }
  __syncthreads();
  if (tid == 0) {
    float S = ss[0] + ss[1] + ss[2] + ss[3];
    float SQ = ssq[0] + ssq[1] + ssq[2] + ssq[3];
    const float invn = 1.0f / (BB * NN);
    float mean = S * invn;
    float var = SQ * invn - mean * mean;
    float a = gamma[c] * rsqrtf(var + 1e-5f);
    ab[c] = make_float2(a, beta[c] - mean * a);
  }
}

// ---------------- BN apply + ReLU, in-place on out ----------------
__global__ void k_bn(float* __restrict__ out, const float2* __restrict__ ab) {
  int idx = blockIdx.x * 256 + threadIdx.x;  // float4 index
  const int total = BB * CC * NN / 4;
  if (idx >= total) return;
  int c = (idx / (NN / 4)) & (CC - 1);
  float2 p = ab[c];
  f32x4 v = ((f32x4*)out)[idx];
  for (int i = 0; i < 4; i++) v[i] = fmaxf(0.f, v[i] * p.x + p.y);
  ((f32x4*)out)[idx] = v;
}

extern "C" void kernel_launch(void* const* d_in, const int* in_sizes, int n_in,
                              void* d_out, int out_size, void* d_ws, size_t ws_size,
                              hipStream_t stream) {
  const float* x = (const float*)d_in[0];
  const float* Wq = (const float*)d_in[1];
  const float* Wk = (const float*)d_in[2];
  const float* Wv = (const float*)d_in[3];
  const float* align_w = (const float*)d_in[4];
  const float* Wfc = (const float*)d_in[5];
  const float* bfc = (const float*)d_in[6];
  const float* gamma = (const float*)d_in[7];
  const float* beta = (const float*)d_in[8];
  float* out = (float*)d_out;

  char* ws = (char*)d_ws;
  const size_t sz_px = (size_t)BB * NN * CC * 2;   // 18,874,368 (also content, aliased)
  const size_t sz_qkv = (size_t)BB * NN * 640 * 2; // 23,592,960
  const size_t sz_vt = (size_t)BB * CC * NN * 2;   // 18,874,368
  unsigned short* px16 = (unsigned short*)(ws);
  unsigned short* qkv = (unsigned short*)(ws + sz_px);
  unsigned short* vt = (unsigned short*)(ws + sz_px + sz_qkv);
  unsigned short* wcat = (unsigned short*)(ws + sz_px + sz_qkv + sz_vt);
  unsigned short* wfc16 = (unsigned short*)(ws + sz_px + sz_qkv + sz_vt + 640 * 512 * 2);
  float2* ab = (float2*)(ws + sz_px + sz_qkv + sz_vt + 640 * 512 * 2 + 512 * 512 * 2);

  k_prep_w<<<(640 * 512 + 512 * 512 + 255) / 256, 256, 0, stream>>>(Wq, Wk, Wv, Wfc, wcat, wfc16);
  k_px<<<dim3(BB, NN / 32, CC / 32), 256, 0, stream>>>(x, px16);
  k_qkv<<<dim3(BB, NN / 64, 5), 256, 0, stream>>>(px16, wcat, align_w, qkv);
  k_vt<<<dim3(BB, NN / 32, CC / 32), 256, 0, stream>>>(qkv, vt);
  k_attn<<<dim3(BB, NN / 32, 2), 256, 0, stream>>>(qkv, vt, px16 /* content in-place */);
  k_fc<<<dim3(CC / 64, BB * NN / 256), 256, 0, stream>>>(px16, wfc16, bfc, out);
  k_stats<<<CC, 256, 0, stream>>>(out, gamma, beta, ab);
  k_bn<<<(BB * CC * NN / 4 + 255) / 256, 256, 0, stream>>>(out, ab);
}

// Round 4
// 224.826 us; speedup vs baseline: 1.8104x; 1.7376x over previous
//
#include <hip/hip_runtime.h>
#include <stdint.h>

#define BB 8
#define CC 512
#define NN 2304
#define NT16 (NN / 16)  // 144
#define NT32 (NN / 32)  // 72
#define CT32 (CC / 32)  // 16

typedef float f32x4 __attribute__((ext_vector_type(4)));
typedef short s16x8 __attribute__((ext_vector_type(8)));

__device__ __forceinline__ unsigned short f2bf(float f) {
  union { float f; uint32_t u; } v; v.f = f;
  uint32_t u = v.u;
  return (unsigned short)((u + 0x7FFFu + ((u >> 16) & 1u)) >> 16);
}
__device__ __forceinline__ float bf2f(unsigned short b) {
  union { uint32_t u; float f; } v; v.u = ((uint32_t)b) << 16;
  return v.f;
}

// Tiled layout everywhere: buf[row/16][k/32][16][32], 1KB tiles matching the MFMA
// fragment (lane l15 = row, 8*lq = k-offset). Fragment load = tile_base + l15*32 + 8*lq
// elements = one contiguous 1KB wave-transaction.

// ---------------- prep: bf16 [Wq|Wk|Wv] rows -> wcat_t tiles; Wfc -> wfc_t tiles ----------------
__global__ void k_prep_w(const float* __restrict__ Wq, const float* __restrict__ Wk,
                         const float* __restrict__ Wv, const float* __restrict__ Wfc,
                         unsigned short* __restrict__ wcat_t, unsigned short* __restrict__ wfc_t) {
  int idx = blockIdx.x * 256 + threadIdx.x;
  const int tot_cat = 640 * 512;
  if (idx < tot_cat) {
    int tile = idx >> 9, inner = idx & 511;
    int j = (tile >> 4) * 16 + (inner >> 5);
    int k = (tile & 15) * 32 + (inner & 31);
    float v = (j < 64) ? Wq[j * 512 + k] : ((j < 128) ? Wk[(j - 64) * 512 + k] : Wv[(j - 128) * 512 + k]);
    wcat_t[idx] = f2bf(v);
  } else if (idx < tot_cat + 512 * 512) {
    int i2 = idx - tot_cat;
    int tile = i2 >> 9, inner = i2 & 511;
    int j = (tile >> 4) * 16 + (inner >> 5);
    int k = (tile & 15) * 32 + (inner & 31);
    wfc_t[i2] = f2bf(Wfc[j * 512 + k]);
  }
}

// ---------------- px_t[(b*NN+n)/16][c/32][16][32] = bf16(x[b][c][n]) ----------------
__global__ void k_px(const float* __restrict__ x, unsigned short* __restrict__ px_t) {
  __shared__ float t[32][33];
  int b = blockIdx.x;
  int nb = blockIdx.y * 32;
  int cb = blockIdx.z * 32;
  int lane = threadIdx.x & 31;
  int row = threadIdx.x >> 5;  // 0..7
  const float* xb = x + (size_t)b * CC * NN;
  for (int rr = 0; rr < 4; rr++) {
    int c = cb + row + 8 * rr;
    t[row + 8 * rr][lane] = xb[(size_t)c * NN + nb + lane];
  }
  __syncthreads();
  int rbase = (b * NN + nb) >> 4;
  int ct = cb >> 5;
  for (int rr = 0; rr < 4; rr++) {
    int nl = row + 8 * rr;  // 0..31
    size_t off = ((size_t)(rbase + (nl >> 4)) * CT32 + ct) * 512 + (nl & 15) * 32 + lane;
    px_t[off] = f2bf(t[lane][nl]);
  }
}

// ---------------- QKV GEMM: q_t/k_t tiled, v_row row-major; tanh/align fused ----------------
__global__ __launch_bounds__(256, 2) void k_qkv(const unsigned short* __restrict__ px_t,
                                                const unsigned short* __restrict__ wcat_t,
                                                const float* __restrict__ align_w,
                                                unsigned short* __restrict__ q_t,
                                                unsigned short* __restrict__ k_t,
                                                unsigned short* __restrict__ v_row) {
  int b = blockIdx.x;
  int nb = blockIdx.y * 64;
  int jb0 = blockIdx.z * 128;
  int tid = threadIdx.x;
  int w = tid >> 6, l = tid & 63, l15 = l & 15, lq = l >> 4;
  int jw = jb0 + 32 * w;
  int loff = l15 * 32 + 8 * lq;
  int rA = (b * NN + nb) >> 4;
  f32x4 acc[4][2];
  for (int mf = 0; mf < 4; mf++) for (int nf = 0; nf < 2; nf++) acc[mf][nf] = (f32x4){0.f, 0.f, 0.f, 0.f};
  for (int kk = 0; kk < 16; kk++) {
    s16x8 a[4], bbf[2];
    for (int mf = 0; mf < 4; mf++)
      a[mf] = *(const s16x8*)(px_t + ((size_t)(rA + mf) * CT32 + kk) * 512 + loff);
    for (int nf = 0; nf < 2; nf++)
      bbf[nf] = *(const s16x8*)(wcat_t + ((size_t)((jw >> 4) + nf) * CT32 + kk) * 512 + loff);
    for (int mf = 0; mf < 4; mf++)
      for (int nf = 0; nf < 2; nf++)
        acc[mf][nf] = __builtin_amdgcn_mfma_f32_16x16x32_bf16(a[mf], bbf[nf], acc[mf][nf], 0, 0, 0);
  }
  for (int mf = 0; mf < 4; mf++)
    for (int nf = 0; nf < 2; nf++)
      for (int r = 0; r < 4; r++) {
        int j = jw + 16 * nf + l15;
        int nl = 4 * lq + r;
        float v = acc[mf][nf][r];
        if (j < 128) { v = tanhf(v); if (j < 64) v *= align_w[j]; }
        unsigned short bv = f2bf(v);
        if (j < 64)
          q_t[((size_t)(rA + mf) * 2 + (j >> 5)) * 512 + nl * 32 + (j & 31)] = bv;
        else if (j < 128) {
          int jj = j - 64;
          k_t[((size_t)(rA + mf) * 2 + (jj >> 5)) * 512 + nl * 32 + (jj & 31)] = bv;
        } else {
          v_row[((size_t)(b * NN) + nb + 16 * mf + nl) * 512 + (j - 128)] = bv;
        }
      }
}

// ---------------- vt_t[b][c/16][n/32][16][32] = transpose of v_row ----------------
__global__ void k_vt(const unsigned short* __restrict__ v_row, unsigned short* __restrict__ vt_t) {
  __shared__ uint32_t t[32][33];
  int b = blockIdx.x;
  int nb = blockIdx.y * 32;
  int cb = blockIdx.z * 32;
  int lane = threadIdx.x & 31;
  int row = threadIdx.x >> 5;
  const unsigned short* src = v_row + (size_t)b * NN * 512;
  for (int rr = 0; rr < 4; rr++) {
    int n = nb + row + 8 * rr;
    t[row + 8 * rr][lane] = (uint32_t)src[(size_t)n * 512 + cb + lane];
  }
  __syncthreads();
  unsigned short* dst = vt_t + (size_t)b * (CC / 16) * NT32 * 512;
  for (int rr = 0; rr < 4; rr++) {
    int c = cb + row + 8 * rr;
    size_t off = ((size_t)(c >> 4) * NT32 + (nb >> 5)) * 512 + (c & 15) * 32 + lane;
    dst[off] = (unsigned short)t[lane][row + 8 * rr];
  }
}

// ---------------- fused attention, i-tile 64, c-split x2 ----------------
// 4 waves: scores j-slice 16/wave (duplicated across c-split), PV c-slice 64/wave.
// All Q/K/V fragment loads are coalesced 1KB tile reads. One raw s_barrier per jt
// iteration (lgkmcnt drain only), double-buffered e_s, K prefetched 1 iter ahead.
__global__ __launch_bounds__(256, 2) void k_attn(const unsigned short* __restrict__ q_t,
                                                 const unsigned short* __restrict__ k_t,
                                                 const unsigned short* __restrict__ vt_t,
                                                 unsigned short* __restrict__ px_t /* content in-place */) {
  __shared__ __align__(16) unsigned short e_s[2][64 * 64];
  __shared__ float rs_s[4][64];
  int b = blockIdx.x;
  int ib = blockIdx.y * 64;
  int ch = blockIdx.z * 256;
  int tid = threadIdx.x;
  int w = tid >> 6, l = tid & 63, l15 = l & 15, lq = l >> 4;
  int c0 = ch + 64 * w;
  int loff = l15 * 32 + 8 * lq;
  int rQ = (b * NN + ib) >> 4;
  int ktb = b * NT16;  // k_t row-tile base for this batch
  const unsigned short* vb = vt_t + (size_t)b * (CC / 16) * NT32 * 512;

  s16x8 qa[4][2];
  for (int mf = 0; mf < 4; mf++)
    for (int ks = 0; ks < 2; ks++)
      qa[mf][ks] = *(const s16x8*)(q_t + ((size_t)(rQ + mf) * 2 + ks) * 512 + loff);

  f32x4 acc[4][4];
  for (int mf = 0; mf < 4; mf++) for (int nf = 0; nf < 4; nf++) acc[mf][nf] = (f32x4){0.f, 0.f, 0.f, 0.f};
  float rs[4][4];
  for (int mf = 0; mf < 4; mf++) for (int r = 0; r < 4; r++) rs[mf][r] = 0.f;

  // prologue: K(0)
  s16x8 kf[2];
  for (int ks = 0; ks < 2; ks++)
    kf[ks] = *(const s16x8*)(k_t + ((size_t)(ktb + w) * 2 + ks) * 512 + loff);

  for (int jt = 0; jt < NN / 64; jt++) {
    int jtn = (jt < NN / 64 - 1) ? jt + 1 : jt;
    // V(t): 8 coalesced 1KB tile loads (used after barrier; never force-drained)
    s16x8 vf[2][4];
    for (int ks = 0; ks < 2; ks++)
      for (int nf = 0; nf < 4; nf++)
        vf[ks][nf] = *(const s16x8*)(vb + ((size_t)((c0 >> 4) + nf) * NT32 + jt * 2 + ks) * 512 + loff);
    // K(t+1) prefetch
    s16x8 kn[2];
    for (int ks = 0; ks < 2; ks++)
      kn[ks] = *(const s16x8*)(k_t + ((size_t)(ktb + jtn * 4 + w) * 2 + ks) * 512 + loff);
    // scores for wave's 16-j slice (i = 64 rows)
    f32x4 sc[4];
    for (int mf = 0; mf < 4; mf++) sc[mf] = (f32x4){0.f, 0.f, 0.f, 0.f};
    for (int ks = 0; ks < 2; ks++)
      for (int mf = 0; mf < 4; mf++)
        sc[mf] = __builtin_amdgcn_mfma_f32_16x16x32_bf16(qa[mf][ks], kf[ks], sc[mf], 0, 0, 0);
    // e = exp(s) (|s| <= 8, no max needed), rowsum partials, stash in e_s[t&1]
    char* ebuf = (char*)e_s[jt & 1];
    for (int mf = 0; mf < 4; mf++)
      for (int r = 0; r < 4; r++) {
        float e = __expf(sc[mf][r]);
        rs[mf][r] += e;
        int i = 16 * mf + 4 * lq + r;
        int byte = (i * 128 + (16 * w + l15) * 2) ^ ((i & 7) << 4);
        *(unsigned short*)(ebuf + byte) = f2bf(e);
      }
    // raw barrier: drain LDS only; global loads stay in flight
    asm volatile("s_waitcnt lgkmcnt(0)" ::: "memory");
    __builtin_amdgcn_s_barrier();
    __builtin_amdgcn_sched_barrier(0);
    // PV: acc[i][c] += e[i][j] * vt[c][j]
    for (int ks = 0; ks < 2; ks++) {
      s16x8 ef[4];
      for (int mf = 0; mf < 4; mf++) {
        int i = 16 * mf + l15;
        int byte = (i * 128 + 64 * ks + 16 * lq) ^ ((i & 7) << 4);
        ef[mf] = *(const s16x8*)(ebuf + byte);
      }
      for (int nf = 0; nf < 4; nf++)
        for (int mf = 0; mf < 4; mf++)
          acc[mf][nf] = __builtin_amdgcn_mfma_f32_16x16x32_bf16(ef[mf], vf[ks][nf], acc[mf][nf], 0, 0, 0);
    }
    kf[0] = kn[0];
    kf[1] = kn[1];
  }

  // rowsum: 16-lane shuffle reduce, then across 4 waves via LDS
  for (int mf = 0; mf < 4; mf++)
    for (int r = 0; r < 4; r++) {
      float v = rs[mf][r];
      v += __shfl_xor(v, 1); v += __shfl_xor(v, 2);
      v += __shfl_xor(v, 4); v += __shfl_xor(v, 8);
      rs[mf][r] = v;
    }
  if (l15 == 0)
    for (int mf = 0; mf < 4; mf++)
      for (int r = 0; r < 4; r++)
        rs_s[w][16 * mf + 4 * lq + r] = rs[mf][r];
  __syncthreads();
  float inv[4][4];
  for (int mf = 0; mf < 4; mf++)
    for (int r = 0; r < 4; r++) {
      int i = 16 * mf + 4 * lq + r;
      inv[mf][r] = 1.0f / (rs_s[0][i] + rs_s[1][i] + rs_s[2][i] + rs_s[3][i]);
    }
  // content = px + attn@v, in-place RMW on px_t (disjoint per lane/block)
  for (int mf = 0; mf < 4; mf++)
    for (int nf = 0; nf < 4; nf++)
      for (int r = 0; r < 4; r++) {
        int i = 16 * mf + 4 * lq + r;
        int bn = b * NN + ib + i;
        int c = c0 + 16 * nf + l15;
        size_t off = ((size_t)(bn >> 4) * CT32 + (c >> 5)) * 512 + (bn & 15) * 32 + (c & 31);
        px_t[off] = f2bf(bf2f(px_t[off]) + acc[mf][nf][r] * inv[mf][r]);
      }
}

// ---------------- FC: out[b][c2][n] = content @ Wfc^T + bfc (tiled A and B reads) ----------------
__global__ __launch_bounds__(256, 2) void k_fc(const unsigned short* __restrict__ px_t,
                                               const unsigned short* __restrict__ wfc_t,
                                               const float* __restrict__ bfc,
                                               float* __restrict__ out) {
  int cb = blockIdx.x * 64;
  int fb = blockIdx.y * 256;
  int tid = threadIdx.x;
  int w = tid >> 6, l = tid & 63, l15 = l & 15, lq = l >> 4;
  int fw = fb + 64 * w;
  int loff = l15 * 32 + 8 * lq;
  f32x4 acc[4][4];
  for (int mf = 0; mf < 4; mf++) for (int nf = 0; nf < 4; nf++) acc[mf][nf] = (f32x4){0.f, 0.f, 0.f, 0.f};
  for (int kk = 0; kk < 16; kk++) {
    s16x8 a[4], bbf[4];
    for (int mf = 0; mf < 4; mf++)
      a[mf] = *(const s16x8*)(wfc_t + ((size_t)((cb >> 4) + mf) * CT32 + kk) * 512 + loff);
    for (int nf = 0; nf < 4; nf++)
      bbf[nf] = *(const s16x8*)(px_t + ((size_t)((fw >> 4) + nf) * CT32 + kk) * 512 + loff);
    for (int mf = 0; mf < 4; mf++)
      for (int nf = 0; nf < 4; nf++)
        acc[mf][nf] = __builtin_amdgcn_mfma_f32_16x16x32_bf16(a[mf], bbf[nf], acc[mf][nf], 0, 0, 0);
  }
  for (int mf = 0; mf < 4; mf++)
    for (int nf = 0; nf < 4; nf++)
      for (int r = 0; r < 4; r++) {
        int c2 = cb + 16 * mf + 4 * lq + r;
        int flat = fw + 16 * nf + l15;
        int b2 = flat / NN;
        int n = flat - b2 * NN;
        out[((size_t)b2 * CC + c2) * NN + n] = acc[mf][nf][r] + bfc[c2];
      }
}

// ---------------- BN stats per channel ----------------
__global__ void k_stats(const float* __restrict__ out, const float* __restrict__ gamma,
                        const float* __restrict__ beta, float2* __restrict__ ab) {
  int c = blockIdx.x;
  int tid = threadIdx.x;
  float s = 0.f, sq = 0.f;
  for (int idx = tid; idx < BB * NN; idx += 256) {
    int b2 = idx / NN, n = idx - b2 * NN;
    float v = out[((size_t)b2 * CC + c) * NN + n];
    s += v; sq += v * v;
  }
  for (int m = 1; m <= 32; m <<= 1) { s += __shfl_xor(s, m); sq += __shfl_xor(sq, m); }
  __shared__ float ss[4], ssq[4];
  int w = tid >> 6;
  if ((tid & 63) == 0) { ss[w] = s; ssq[w] = sq; }
  __syncthreads();
  if (tid == 0) {
    float S = ss[0] + ss[1] + ss[2] + ss[3];
    float SQ = ssq[0] + ssq[1] + ssq[2] + ssq[3];
    const float invn = 1.0f / (BB * NN);
    float mean = S * invn;
    float var = SQ * invn - mean * mean;
    float a = gamma[c] * rsqrtf(var + 1e-5f);
    ab[c] = make_float2(a, beta[c] - mean * a);
  }
}

// ---------------- BN apply + ReLU, in-place on out ----------------
__global__ void k_bn(float* __restrict__ out, const float2* __restrict__ ab) {
  int idx = blockIdx.x * 256 + threadIdx.x;  // float4 index
  const int total = BB * CC * NN / 4;
  if (idx >= total) return;
  int c = (idx / (NN / 4)) & (CC - 1);
  float2 p = ab[c];
  f32x4 v = ((f32x4*)out)[idx];
  for (int i = 0; i < 4; i++) v[i] = fmaxf(0.f, v[i] * p.x + p.y);
  ((f32x4*)out)[idx] = v;
}

extern "C" void kernel_launch(void* const* d_in, const int* in_sizes, int n_in,
                              void* d_out, int out_size, void* d_ws, size_t ws_size,
                              hipStream_t stream) {
  const float* x = (const float*)d_in[0];
  const float* Wq = (const float*)d_in[1];
  const float* Wk = (const float*)d_in[2];
  const float* Wv = (const float*)d_in[3];
  const float* align_w = (const float*)d_in[4];
  const float* Wfc = (const float*)d_in[5];
  const float* bfc = (const float*)d_in[6];
  const float* gamma = (const float*)d_in[7];
  const float* beta = (const float*)d_in[8];
  float* out = (float*)d_out;

  char* ws = (char*)d_ws;
  const size_t sz_px = (size_t)BB * NN * CC * 2;  // 18,874,368 (px_t / content, in-place)
  const size_t sz_q = (size_t)BB * NN * 64 * 2;   // 2,359,296
  const size_t sz_vr = (size_t)BB * NN * CC * 2;  // 18,874,368
  unsigned short* px_t = (unsigned short*)(ws);
  unsigned short* q_t = (unsigned short*)(ws + sz_px);
  unsigned short* k_t = (unsigned short*)(ws + sz_px + sz_q);
  unsigned short* v_row = (unsigned short*)(ws + sz_px + 2 * sz_q);
  unsigned short* vt_t = (unsigned short*)(ws + sz_px + 2 * sz_q + sz_vr);
  unsigned short* wcat_t = (unsigned short*)(ws + sz_px + 2 * sz_q + 2 * sz_vr);
  unsigned short* wfc_t = (unsigned short*)(ws + sz_px + 2 * sz_q + 2 * sz_vr + 640 * 512 * 2);
  float2* ab = (float2*)(ws + sz_px + 2 * sz_q + 2 * sz_vr + 640 * 512 * 2 + 512 * 512 * 2);

  k_prep_w<<<(640 * 512 + 512 * 512 + 255) / 256, 256, 0, stream>>>(Wq, Wk, Wv, Wfc, wcat_t, wfc_t);
  k_px<<<dim3(BB, NN / 32, CC / 32), 256, 0, stream>>>(x, px_t);
  k_qkv<<<dim3(BB, NN / 64, 5), 256, 0, stream>>>(px_t, wcat_t, align_w, q_t, k_t, v_row);
  k_vt<<<dim3(BB, NN / 32, CC / 32), 256, 0, stream>>>(v_row, vt_t);
  k_attn<<<dim3(BB, NN / 64, 2), 256, 0, stream>>>(q_t, k_t, vt_t, px_t);
  k_fc<<<dim3(CC / 64, BB * NN / 256), 256, 0, stream>>>(px_t, wfc_t, bfc, out);
  k_stats<<<CC, 256, 0, stream>>>(out, gamma, beta, ab);
  k_bn<<<(BB * CC * NN / 4 + 255) / 256, 256, 0, stream>>>(out, ab);
}

// Round 5
// 204.178 us; speedup vs baseline: 1.9935x; 1.1011x over previous
//
#include <hip/hip_runtime.h>
#include <stdint.h>

#define BB 8
#define CC 512
#define NN 2304
#define NT16 (NN / 16)  // 144
#define NT32 (NN / 32)  // 72
#define CT32 (CC / 32)  // 16
#define NYB 48          // k_fc y-blocks (stats partials)

typedef float f32x4 __attribute__((ext_vector_type(4)));
typedef short s16x8 __attribute__((ext_vector_type(8)));

__device__ __forceinline__ unsigned short f2bf(float f) {
  union { float f; uint32_t u; } v; v.f = f;
  uint32_t u = v.u;
  return (unsigned short)((u + 0x7FFFu + ((u >> 16) & 1u)) >> 16);
}
__device__ __forceinline__ float bf2f(unsigned short b) {
  union { uint32_t u; float f; } v; v.u = ((uint32_t)b) << 16;
  return v.f;
}

// Tiled layout everywhere: buf[row/16][k/32][16][32], 1KB tiles matching the MFMA
// fragment (lane l15 = row, 8*lq = k-offset). Fragment load = one contiguous 1KB
// wave-transaction (R4 win: 217us -> 91us on k_attn).

// ---------------- prep: bf16 [Wq|Wk|Wv] rows -> wcat_t tiles; Wfc -> wfc_t tiles ----------------
__global__ void k_prep_w(const float* __restrict__ Wq, const float* __restrict__ Wk,
                         const float* __restrict__ Wv, const float* __restrict__ Wfc,
                         unsigned short* __restrict__ wcat_t, unsigned short* __restrict__ wfc_t) {
  int idx = blockIdx.x * 256 + threadIdx.x;
  const int tot_cat = 640 * 512;
  if (idx < tot_cat) {
    int tile = idx >> 9, inner = idx & 511;
    int j = (tile >> 4) * 16 + (inner >> 5);
    int k = (tile & 15) * 32 + (inner & 31);
    float v = (j < 64) ? Wq[j * 512 + k] : ((j < 128) ? Wk[(j - 64) * 512 + k] : Wv[(j - 128) * 512 + k]);
    wcat_t[idx] = f2bf(v);
  } else if (idx < tot_cat + 512 * 512) {
    int i2 = idx - tot_cat;
    int tile = i2 >> 9, inner = i2 & 511;
    int j = (tile >> 4) * 16 + (inner >> 5);
    int k = (tile & 15) * 32 + (inner & 31);
    wfc_t[i2] = f2bf(Wfc[j * 512 + k]);
  }
}

// ---------------- px_t[(b*NN+n)/16][c/32][16][32] = bf16(x[b][c][n]) ----------------
__global__ void k_px(const float* __restrict__ x, unsigned short* __restrict__ px_t) {
  __shared__ float t[32][33];
  int b = blockIdx.x;
  int nb = blockIdx.y * 32;
  int cb = blockIdx.z * 32;
  int lane = threadIdx.x & 31;
  int row = threadIdx.x >> 5;  // 0..7
  const float* xb = x + (size_t)b * CC * NN;
  for (int rr = 0; rr < 4; rr++) {
    int c = cb + row + 8 * rr;
    t[row + 8 * rr][lane] = xb[(size_t)c * NN + nb + lane];
  }
  __syncthreads();
  int rbase = (b * NN + nb) >> 4;
  int ct = cb >> 5;
  for (int rr = 0; rr < 4; rr++) {
    int nl = row + 8 * rr;  // 0..31
    size_t off = ((size_t)(rbase + (nl >> 4)) * CT32 + ct) * 512 + (nl & 15) * 32 + lane;
    px_t[off] = f2bf(t[lane][nl]);
  }
}

// ---------------- QKV GEMM: q_t/k_t tiled, v_row row-major; tanh/align fused ----------------
__global__ __launch_bounds__(256, 2) void k_qkv(const unsigned short* __restrict__ px_t,
                                                const unsigned short* __restrict__ wcat_t,
                                                const float* __restrict__ align_w,
                                                unsigned short* __restrict__ q_t,
                                                unsigned short* __restrict__ k_t,
                                                unsigned short* __restrict__ v_row) {
  int b = blockIdx.x;
  int nb = blockIdx.y * 64;
  int jb0 = blockIdx.z * 128;
  int tid = threadIdx.x;
  int w = tid >> 6, l = tid & 63, l15 = l & 15, lq = l >> 4;
  int jw = jb0 + 32 * w;
  int loff = l15 * 32 + 8 * lq;
  int rA = (b * NN + nb) >> 4;
  f32x4 acc[4][2];
  for (int mf = 0; mf < 4; mf++) for (int nf = 0; nf < 2; nf++) acc[mf][nf] = (f32x4){0.f, 0.f, 0.f, 0.f};
  for (int kk = 0; kk < 16; kk++) {
    s16x8 a[4], bbf[2];
    for (int mf = 0; mf < 4; mf++)
      a[mf] = *(const s16x8*)(px_t + ((size_t)(rA + mf) * CT32 + kk) * 512 + loff);
    for (int nf = 0; nf < 2; nf++)
      bbf[nf] = *(const s16x8*)(wcat_t + ((size_t)((jw >> 4) + nf) * CT32 + kk) * 512 + loff);
    for (int mf = 0; mf < 4; mf++)
      for (int nf = 0; nf < 2; nf++)
        acc[mf][nf] = __builtin_amdgcn_mfma_f32_16x16x32_bf16(a[mf], bbf[nf], acc[mf][nf], 0, 0, 0);
  }
  for (int mf = 0; mf < 4; mf++)
    for (int nf = 0; nf < 2; nf++)
      for (int r = 0; r < 4; r++) {
        int j = jw + 16 * nf + l15;
        int nl = 4 * lq + r;
        float v = acc[mf][nf][r];
        if (j < 128) { v = tanhf(v); if (j < 64) v *= align_w[j]; }
        unsigned short bv = f2bf(v);
        if (j < 64)
          q_t[((size_t)(rA + mf) * 2 + (j >> 5)) * 512 + nl * 32 + (j & 31)] = bv;
        else if (j < 128) {
          int jj = j - 64;
          k_t[((size_t)(rA + mf) * 2 + (jj >> 5)) * 512 + nl * 32 + (jj & 31)] = bv;
        } else {
          v_row[((size_t)(b * NN) + nb + 16 * mf + nl) * 512 + (j - 128)] = bv;
        }
      }
}

// ---------------- vt_t[b][c/16][n/32][16][32] = transpose of v_row ----------------
__global__ void k_vt(const unsigned short* __restrict__ v_row, unsigned short* __restrict__ vt_t) {
  __shared__ uint32_t t[32][33];
  int b = blockIdx.x;
  int nb = blockIdx.y * 32;
  int cb = blockIdx.z * 32;
  int lane = threadIdx.x & 31;
  int row = threadIdx.x >> 5;
  const unsigned short* src = v_row + (size_t)b * NN * 512;
  for (int rr = 0; rr < 4; rr++) {
    int n = nb + row + 8 * rr;
    t[row + 8 * rr][lane] = (uint32_t)src[(size_t)n * 512 + cb + lane];
  }
  __syncthreads();
  unsigned short* dst = vt_t + (size_t)b * (CC / 16) * NT32 * 512;
  for (int rr = 0; rr < 4; rr++) {
    int c = cb + row + 8 * rr;
    size_t off = ((size_t)(c >> 4) * NT32 + (nb >> 5)) * 512 + (c & 15) * 32 + lane;
    dst[off] = (unsigned short)t[lane][row + 8 * rr];
  }
}

// ---------------- fused attention, i-tile 48, c-split x2 ----------------
// grid (8, 48, 2) = 768 blocks = exactly 3 blocks/CU resident, zero tail.
// 4 waves: scores j-slice 16/wave, PV c-slice 64/wave. Coalesced 1KB tile fragment
// loads. One raw s_barrier per jt iteration (lgkmcnt drain only), double-buffered
// e_s, K prefetched 1 iter ahead.
__global__ __launch_bounds__(256, 3) void k_attn(const unsigned short* __restrict__ q_t,
                                                 const unsigned short* __restrict__ k_t,
                                                 const unsigned short* __restrict__ vt_t,
                                                 unsigned short* __restrict__ px_t /* content in-place */) {
  __shared__ __align__(16) unsigned short e_s[2][48 * 64];
  __shared__ float rs_s[4][48];
  int b = blockIdx.x;
  int ib = blockIdx.y * 48;
  int ch = blockIdx.z * 256;
  int tid = threadIdx.x;
  int w = tid >> 6, l = tid & 63, l15 = l & 15, lq = l >> 4;
  int c0 = ch + 64 * w;
  int loff = l15 * 32 + 8 * lq;
  int rQ = (b * NN + ib) >> 4;
  int ktb = b * NT16;  // k_t row-tile base for this batch
  const unsigned short* vb = vt_t + (size_t)b * (CC / 16) * NT32 * 512;

  s16x8 qa[3][2];
  for (int mf = 0; mf < 3; mf++)
    for (int ks = 0; ks < 2; ks++)
      qa[mf][ks] = *(const s16x8*)(q_t + ((size_t)(rQ + mf) * 2 + ks) * 512 + loff);

  f32x4 acc[3][4];
  for (int mf = 0; mf < 3; mf++) for (int nf = 0; nf < 4; nf++) acc[mf][nf] = (f32x4){0.f, 0.f, 0.f, 0.f};
  float rs[3][4];
  for (int mf = 0; mf < 3; mf++) for (int r = 0; r < 4; r++) rs[mf][r] = 0.f;

  // prologue: K(0)
  s16x8 kf[2];
  for (int ks = 0; ks < 2; ks++)
    kf[ks] = *(const s16x8*)(k_t + ((size_t)(ktb + w) * 2 + ks) * 512 + loff);

  for (int jt = 0; jt < NN / 64; jt++) {
    int jtn = (jt < NN / 64 - 1) ? jt + 1 : jt;
    // V(t): 8 coalesced 1KB tile loads (used after barrier; never force-drained)
    s16x8 vf[2][4];
    for (int ks = 0; ks < 2; ks++)
      for (int nf = 0; nf < 4; nf++)
        vf[ks][nf] = *(const s16x8*)(vb + ((size_t)((c0 >> 4) + nf) * NT32 + jt * 2 + ks) * 512 + loff);
    // K(t+1) prefetch
    s16x8 kn[2];
    for (int ks = 0; ks < 2; ks++)
      kn[ks] = *(const s16x8*)(k_t + ((size_t)(ktb + jtn * 4 + w) * 2 + ks) * 512 + loff);
    // scores for wave's 16-j slice (i = 48 rows)
    f32x4 sc[3];
    for (int mf = 0; mf < 3; mf++) sc[mf] = (f32x4){0.f, 0.f, 0.f, 0.f};
    for (int ks = 0; ks < 2; ks++)
      for (int mf = 0; mf < 3; mf++)
        sc[mf] = __builtin_amdgcn_mfma_f32_16x16x32_bf16(qa[mf][ks], kf[ks], sc[mf], 0, 0, 0);
    // e = exp(s) (|s| <= 8, no max needed), rowsum partials, stash in e_s[t&1]
    char* ebuf = (char*)e_s[jt & 1];
    for (int mf = 0; mf < 3; mf++)
      for (int r = 0; r < 4; r++) {
        float e = __expf(sc[mf][r]);
        rs[mf][r] += e;
        int i = 16 * mf + 4 * lq + r;
        int byte = (i * 128 + (16 * w + l15) * 2) ^ ((i & 7) << 4);
        *(unsigned short*)(ebuf + byte) = f2bf(e);
      }
    // raw barrier: drain LDS only; global loads stay in flight
    asm volatile("s_waitcnt lgkmcnt(0)" ::: "memory");
    __builtin_amdgcn_s_barrier();
    __builtin_amdgcn_sched_barrier(0);
    // PV: acc[i][c] += e[i][j] * vt[c][j]
    for (int ks = 0; ks < 2; ks++) {
      s16x8 ef[3];
      for (int mf = 0; mf < 3; mf++) {
        int i = 16 * mf + l15;
        int byte = (i * 128 + 64 * ks + 16 * lq) ^ ((i & 7) << 4);
        ef[mf] = *(const s16x8*)(ebuf + byte);
      }
      for (int nf = 0; nf < 4; nf++)
        for (int mf = 0; mf < 3; mf++)
          acc[mf][nf] = __builtin_amdgcn_mfma_f32_16x16x32_bf16(ef[mf], vf[ks][nf], acc[mf][nf], 0, 0, 0);
    }
    kf[0] = kn[0];
    kf[1] = kn[1];
  }

  // rowsum: 16-lane shuffle reduce, then across 4 waves via LDS
  for (int mf = 0; mf < 3; mf++)
    for (int r = 0; r < 4; r++) {
      float v = rs[mf][r];
      v += __shfl_xor(v, 1); v += __shfl_xor(v, 2);
      v += __shfl_xor(v, 4); v += __shfl_xor(v, 8);
      rs[mf][r] = v;
    }
  if (l15 == 0)
    for (int mf = 0; mf < 3; mf++)
      for (int r = 0; r < 4; r++)
        rs_s[w][16 * mf + 4 * lq + r] = rs[mf][r];
  __syncthreads();
  float inv[3][4];
  for (int mf = 0; mf < 3; mf++)
    for (int r = 0; r < 4; r++) {
      int i = 16 * mf + 4 * lq + r;
      inv[mf][r] = 1.0f / (rs_s[0][i] + rs_s[1][i] + rs_s[2][i] + rs_s[3][i]);
    }
  // content = px + attn@v, in-place RMW on px_t (disjoint per lane/block)
  for (int mf = 0; mf < 3; mf++)
    for (int nf = 0; nf < 4; nf++)
      for (int r = 0; r < 4; r++) {
        int i = 16 * mf + 4 * lq + r;
        int bn = b * NN + ib + i;
        int c = c0 + 16 * nf + l15;
        size_t off = ((size_t)(bn >> 4) * CT32 + (c >> 5)) * 512 + (bn & 15) * 32 + (c & 31);
        px_t[off] = f2bf(bf2f(px_t[off]) + acc[mf][nf][r] * inv[mf][r]);
      }
}

// ---------------- FC + fused BN partial stats ----------------
// grid (16, 48) = 768 = 3/CU. Per block: 32 channels x 384 flat. Deterministic
// per-block stats partials[c][yb] (no atomics) replace the full-re-read k_stats.
__global__ __launch_bounds__(256, 3) void k_fc(const unsigned short* __restrict__ px_t,
                                               const unsigned short* __restrict__ wfc_t,
                                               const float* __restrict__ bfc,
                                               float* __restrict__ out,
                                               float2* __restrict__ partials) {
  __shared__ float pss[4][32], psq[4][32];
  int cb = blockIdx.x * 32;
  int yb = blockIdx.y;
  int fb = yb * 384;
  int tid = threadIdx.x;
  int w = tid >> 6, l = tid & 63, l15 = l & 15, lq = l >> 4;
  int fw = fb + 96 * w;
  int loff = l15 * 32 + 8 * lq;
  f32x4 acc[2][6];
  for (int mf = 0; mf < 2; mf++) for (int nf = 0; nf < 6; nf++) acc[mf][nf] = (f32x4){0.f, 0.f, 0.f, 0.f};
  for (int kk = 0; kk < 16; kk++) {
    s16x8 a[2], bbf[6];
    for (int mf = 0; mf < 2; mf++)
      a[mf] = *(const s16x8*)(wfc_t + ((size_t)((cb >> 4) + mf) * CT32 + kk) * 512 + loff);
    for (int nf = 0; nf < 6; nf++)
      bbf[nf] = *(const s16x8*)(px_t + ((size_t)((fw >> 4) + nf) * CT32 + kk) * 512 + loff);
    for (int mf = 0; mf < 2; mf++)
      for (int nf = 0; nf < 6; nf++)
        acc[mf][nf] = __builtin_amdgcn_mfma_f32_16x16x32_bf16(a[mf], bbf[nf], acc[mf][nf], 0, 0, 0);
  }
  float s8[2][4], q8[2][4];
  for (int mf = 0; mf < 2; mf++)
    for (int r = 0; r < 4; r++) {
      int c2 = cb + 16 * mf + 4 * lq + r;
      float bias = bfc[c2];
      float s = 0.f, q = 0.f;
      for (int nf = 0; nf < 6; nf++) {
        float v = acc[mf][nf][r] + bias;
        int flat = fw + 16 * nf + l15;
        int b2 = flat / NN;
        int n = flat - b2 * NN;
        out[((size_t)b2 * CC + c2) * NN + n] = v;
        s += v; q += v * v;
      }
      s8[mf][r] = s; q8[mf][r] = q;
    }
  // reduce over the 16-lane (l15) group
  for (int mf = 0; mf < 2; mf++)
    for (int r = 0; r < 4; r++) {
      float s = s8[mf][r], q = q8[mf][r];
      s += __shfl_xor(s, 1); q += __shfl_xor(q, 1);
      s += __shfl_xor(s, 2); q += __shfl_xor(q, 2);
      s += __shfl_xor(s, 4); q += __shfl_xor(q, 4);
      s += __shfl_xor(s, 8); q += __shfl_xor(q, 8);
      s8[mf][r] = s; q8[mf][r] = q;
    }
  if (l15 == 0)
    for (int mf = 0; mf < 2; mf++)
      for (int r = 0; r < 4; r++) {
        int idx = 16 * mf + 4 * lq + r;
        pss[w][idx] = s8[mf][r];
        psq[w][idx] = q8[mf][r];
      }
  __syncthreads();
  if (tid < 32) {
    float s = pss[0][tid] + pss[1][tid] + pss[2][tid] + pss[3][tid];
    float q = psq[0][tid] + psq[1][tid] + psq[2][tid] + psq[3][tid];
    partials[(size_t)(cb + tid) * NYB + yb] = make_float2(s, q);
  }
}

// ---------------- BN stats finalize: 512 channels, read 48 partials each ----------------
__global__ void k_stats2(const float2* __restrict__ partials, const float* __restrict__ gamma,
                         const float* __restrict__ beta, float2* __restrict__ ab) {
  int c = blockIdx.x * 256 + threadIdx.x;
  if (c >= CC) return;
  float s = 0.f, q = 0.f;
  for (int i = 0; i < NYB; i++) {
    float2 p = partials[(size_t)c * NYB + i];
    s += p.x; q += p.y;
  }
  const float invn = 1.0f / (BB * NN);
  float mean = s * invn;
  float var = q * invn - mean * mean;
  float a = gamma[c] * rsqrtf(var + 1e-5f);
  ab[c] = make_float2(a, beta[c] - mean * a);
}

// ---------------- BN apply + ReLU, in-place on out ----------------
__global__ void k_bn(float* __restrict__ out, const float2* __restrict__ ab) {
  int idx = blockIdx.x * 256 + threadIdx.x;  // float4 index
  const int total = BB * CC * NN / 4;
  if (idx >= total) return;
  int c = (idx / (NN / 4)) & (CC - 1);
  float2 p = ab[c];
  f32x4 v = ((f32x4*)out)[idx];
  for (int i = 0; i < 4; i++) v[i] = fmaxf(0.f, v[i] * p.x + p.y);
  ((f32x4*)out)[idx] = v;
}

extern "C" void kernel_launch(void* const* d_in, const int* in_sizes, int n_in,
                              void* d_out, int out_size, void* d_ws, size_t ws_size,
                              hipStream_t stream) {
  const float* x = (const float*)d_in[0];
  const float* Wq = (const float*)d_in[1];
  const float* Wk = (const float*)d_in[2];
  const float* Wv = (const float*)d_in[3];
  const float* align_w = (const float*)d_in[4];
  const float* Wfc = (const float*)d_in[5];
  const float* bfc = (const float*)d_in[6];
  const float* gamma = (const float*)d_in[7];
  const float* beta = (const float*)d_in[8];
  float* out = (float*)d_out;

  char* ws = (char*)d_ws;
  const size_t sz_px = (size_t)BB * NN * CC * 2;  // 18,874,368 (px_t / content, in-place)
  const size_t sz_q = (size_t)BB * NN * 64 * 2;   // 2,359,296
  const size_t sz_vr = (size_t)BB * NN * CC * 2;  // 18,874,368
  unsigned short* px_t = (unsigned short*)(ws);
  unsigned short* q_t = (unsigned short*)(ws + sz_px);
  unsigned short* k_t = (unsigned short*)(ws + sz_px + sz_q);
  unsigned short* v_row = (unsigned short*)(ws + sz_px + 2 * sz_q);
  unsigned short* vt_t = (unsigned short*)(ws + sz_px + 2 * sz_q + sz_vr);
  unsigned short* wcat_t = (unsigned short*)(ws + sz_px + 2 * sz_q + 2 * sz_vr);
  unsigned short* wfc_t = (unsigned short*)(ws + sz_px + 2 * sz_q + 2 * sz_vr + 640 * 512 * 2);
  float2* partials = (float2*)(ws + sz_px + 2 * sz_q + 2 * sz_vr + 640 * 512 * 2 + 512 * 512 * 2);
  float2* ab = (float2*)((char*)partials + (size_t)CC * NYB * sizeof(float2));

  k_prep_w<<<(640 * 512 + 512 * 512 + 255) / 256, 256, 0, stream>>>(Wq, Wk, Wv, Wfc, wcat_t, wfc_t);
  k_px<<<dim3(BB, NN / 32, CC / 32), 256, 0, stream>>>(x, px_t);
  k_qkv<<<dim3(BB, NN / 64, 5), 256, 0, stream>>>(px_t, wcat_t, align_w, q_t, k_t, v_row);
  k_vt<<<dim3(BB, NN / 32, CC / 32), 256, 0, stream>>>(v_row, vt_t);
  k_attn<<<dim3(BB, NN / 48, 2), 256, 0, stream>>>(q_t, k_t, vt_t, px_t);
  k_fc<<<dim3(CC / 32, NYB), 256, 0, stream>>>(px_t, wfc_t, bfc, out, partials);
  k_stats2<<<2, 256, 0, stream>>>(partials, gamma, beta, ab);
  k_bn<<<(BB * CC * NN / 4 + 255) / 256, 256, 0, stream>>>(out, ab);
}

// Round 6
// 198.400 us; speedup vs baseline: 2.0515x; 1.0291x over previous
//
#include <hip/hip_runtime.h>
#include <stdint.h>

#define BB 8
#define CC 512
#define NN 2304
#define NT16 (NN / 16)  // 144
#define NT32 (NN / 32)  // 72
#define CT32 (CC / 32)  // 16
#define NYB 48          // k_fc y-blocks (stats partials)

typedef float f32x4 __attribute__((ext_vector_type(4)));
typedef short s16x8 __attribute__((ext_vector_type(8)));

__device__ __forceinline__ unsigned short f2bf(float f) {
  union { float f; uint32_t u; } v; v.f = f;
  uint32_t u = v.u;
  return (unsigned short)((u + 0x7FFFu + ((u >> 16) & 1u)) >> 16);
}
__device__ __forceinline__ float bf2f(unsigned short b) {
  union { uint32_t u; float f; } v; v.u = ((uint32_t)b) << 16;
  return v.f;
}

// Tiled layout everywhere: buf[row/16][k/32][16][32], 1KB tiles matching the MFMA
// fragment (lane l15 = row, 8*lq = k-offset). Fragment load = one contiguous 1KB
// wave-transaction (R4 win: 217us -> 91us on k_attn).

// ---------------- prep: bf16 [Wq|Wk|Wv] rows -> wcat_t tiles; Wfc -> wfc_t tiles ----------------
__global__ void k_prep_w(const float* __restrict__ Wq, const float* __restrict__ Wk,
                         const float* __restrict__ Wv, const float* __restrict__ Wfc,
                         unsigned short* __restrict__ wcat_t, unsigned short* __restrict__ wfc_t) {
  int idx = blockIdx.x * 256 + threadIdx.x;
  const int tot_cat = 640 * 512;
  if (idx < tot_cat) {
    int tile = idx >> 9, inner = idx & 511;
    int j = (tile >> 4) * 16 + (inner >> 5);
    int k = (tile & 15) * 32 + (inner & 31);
    float v = (j < 64) ? Wq[j * 512 + k] : ((j < 128) ? Wk[(j - 64) * 512 + k] : Wv[(j - 128) * 512 + k]);
    wcat_t[idx] = f2bf(v);
  } else if (idx < tot_cat + 512 * 512) {
    int i2 = idx - tot_cat;
    int tile = i2 >> 9, inner = i2 & 511;
    int j = (tile >> 4) * 16 + (inner >> 5);
    int k = (tile & 15) * 32 + (inner & 31);
    wfc_t[i2] = f2bf(Wfc[j * 512 + k]);
  }
}

// ---------------- px_t[(b*NN+n)/16][c/32][16][32] = bf16(x[b][c][n]) ----------------
__global__ void k_px(const float* __restrict__ x, unsigned short* __restrict__ px_t) {
  __shared__ float t[32][33];
  int b = blockIdx.x;
  int nb = blockIdx.y * 32;
  int cb = blockIdx.z * 32;
  int lane = threadIdx.x & 31;
  int row = threadIdx.x >> 5;  // 0..7
  const float* xb = x + (size_t)b * CC * NN;
  for (int rr = 0; rr < 4; rr++) {
    int c = cb + row + 8 * rr;
    t[row + 8 * rr][lane] = xb[(size_t)c * NN + nb + lane];
  }
  __syncthreads();
  int rbase = (b * NN + nb) >> 4;
  int ct = cb >> 5;
  for (int rr = 0; rr < 4; rr++) {
    int nl = row + 8 * rr;  // 0..31
    size_t off = ((size_t)(rbase + (nl >> 4)) * CT32 + ct) * 512 + (nl & 15) * 32 + lane;
    px_t[off] = f2bf(t[lane][nl]);
  }
}

// ---------------- QKV GEMM: q_t/k_t tiled, v_row row-major; tanh/align fused ----------------
__global__ __launch_bounds__(256, 2) void k_qkv(const unsigned short* __restrict__ px_t,
                                                const unsigned short* __restrict__ wcat_t,
                                                const float* __restrict__ align_w,
                                                unsigned short* __restrict__ q_t,
                                                unsigned short* __restrict__ k_t,
                                                unsigned short* __restrict__ v_row) {
  int b = blockIdx.x;
  int nb = blockIdx.y * 64;
  int jb0 = blockIdx.z * 128;
  int tid = threadIdx.x;
  int w = tid >> 6, l = tid & 63, l15 = l & 15, lq = l >> 4;
  int jw = jb0 + 32 * w;
  int loff = l15 * 32 + 8 * lq;
  int rA = (b * NN + nb) >> 4;
  f32x4 acc[4][2];
  for (int mf = 0; mf < 4; mf++) for (int nf = 0; nf < 2; nf++) acc[mf][nf] = (f32x4){0.f, 0.f, 0.f, 0.f};
  for (int kk = 0; kk < 16; kk++) {
    s16x8 a[4], bbf[2];
    for (int mf = 0; mf < 4; mf++)
      a[mf] = *(const s16x8*)(px_t + ((size_t)(rA + mf) * CT32 + kk) * 512 + loff);
    for (int nf = 0; nf < 2; nf++)
      bbf[nf] = *(const s16x8*)(wcat_t + ((size_t)((jw >> 4) + nf) * CT32 + kk) * 512 + loff);
    for (int mf = 0; mf < 4; mf++)
      for (int nf = 0; nf < 2; nf++)
        acc[mf][nf] = __builtin_amdgcn_mfma_f32_16x16x32_bf16(a[mf], bbf[nf], acc[mf][nf], 0, 0, 0);
  }
  for (int mf = 0; mf < 4; mf++)
    for (int nf = 0; nf < 2; nf++)
      for (int r = 0; r < 4; r++) {
        int j = jw + 16 * nf + l15;
        int nl = 4 * lq + r;
        float v = acc[mf][nf][r];
        if (j < 128) { v = tanhf(v); if (j < 64) v *= align_w[j]; }
        unsigned short bv = f2bf(v);
        if (j < 64)
          q_t[((size_t)(rA + mf) * 2 + (j >> 5)) * 512 + nl * 32 + (j & 31)] = bv;
        else if (j < 128) {
          int jj = j - 64;
          k_t[((size_t)(rA + mf) * 2 + (jj >> 5)) * 512 + nl * 32 + (jj & 31)] = bv;
        } else {
          v_row[((size_t)(b * NN) + nb + 16 * mf + nl) * 512 + (j - 128)] = bv;
        }
      }
}

// ---------------- vt_t[b][c/16][n/32][16][32] = transpose of v_row ----------------
__global__ void k_vt(const unsigned short* __restrict__ v_row, unsigned short* __restrict__ vt_t) {
  __shared__ uint32_t t[32][33];
  int b = blockIdx.x;
  int nb = blockIdx.y * 32;
  int cb = blockIdx.z * 32;
  int lane = threadIdx.x & 31;
  int row = threadIdx.x >> 5;
  const unsigned short* src = v_row + (size_t)b * NN * 512;
  for (int rr = 0; rr < 4; rr++) {
    int n = nb + row + 8 * rr;
    t[row + 8 * rr][lane] = (uint32_t)src[(size_t)n * 512 + cb + lane];
  }
  __syncthreads();
  unsigned short* dst = vt_t + (size_t)b * (CC / 16) * NT32 * 512;
  for (int rr = 0; rr < 4; rr++) {
    int c = cb + row + 8 * rr;
    size_t off = ((size_t)(c >> 4) * NT32 + (nb >> 5)) * 512 + (c & 15) * 32 + lane;
    dst[off] = (unsigned short)t[lane][row + 8 * rr];
  }
}

// ---------------- fused attention, i-tile 48, c-split x2, E-pipelined ----------------
// grid (8, 48, 2) = 768 blocks = exactly 3 blocks/CU, zero tail.
// R6: software-pipelined E-tile — iteration t computes scores(t)->ebuf[t&1] AND
// PV(t-1) from ebuf[(t-1)&1] + vf_prev (all operands ready at iteration start, so
// the ~24 PV MFMAs interleave with the scores->exp->ds_write chain). ONE raw
// s_barrier + lgkmcnt(0) per iteration (no vmcnt drain). Hazards: ebuf[t&1]
// writes occur after barrier(t-1); its previous readers (PV(t-2), in iter t-1)
// drained at lgkmcnt(0) before barrier(t-1).
__global__ __launch_bounds__(256, 3) void k_attn(const unsigned short* __restrict__ q_t,
                                                 const unsigned short* __restrict__ k_t,
                                                 const unsigned short* __restrict__ vt_t,
                                                 unsigned short* __restrict__ px_t /* content in-place */) {
  __shared__ __align__(16) unsigned short e_s[2][48 * 64];
  __shared__ float rs_s[4][48];
  int b = blockIdx.x;
  int ib = blockIdx.y * 48;
  int ch = blockIdx.z * 256;
  int tid = threadIdx.x;
  int w = tid >> 6, l = tid & 63, l15 = l & 15, lq = l >> 4;
  int c0 = ch + 64 * w;
  int loff = l15 * 32 + 8 * lq;
  int rQ = (b * NN + ib) >> 4;
  int ktb = b * NT16;
  const unsigned short* vb = vt_t + (size_t)b * (CC / 16) * NT32 * 512;

  s16x8 qa[3][2];
  for (int mf = 0; mf < 3; mf++)
    for (int ks = 0; ks < 2; ks++)
      qa[mf][ks] = *(const s16x8*)(q_t + ((size_t)(rQ + mf) * 2 + ks) * 512 + loff);

  f32x4 acc[3][4];
  for (int mf = 0; mf < 3; mf++) for (int nf = 0; nf < 4; nf++) acc[mf][nf] = (f32x4){0.f, 0.f, 0.f, 0.f};
  float rs[3][4];
  for (int mf = 0; mf < 3; mf++) for (int r = 0; r < 4; r++) rs[mf][r] = 0.f;

  // ---- prologue: K(0); iteration 0 (scores only, no PV) ----
  s16x8 kf[2];
  for (int ks = 0; ks < 2; ks++)
    kf[ks] = *(const s16x8*)(k_t + ((size_t)(ktb + w) * 2 + ks) * 512 + loff);

  s16x8 vfp[2][4];  // V(t-1) carried into next iteration
  for (int ks = 0; ks < 2; ks++)
    for (int nf = 0; nf < 4; nf++)
      vfp[ks][nf] = *(const s16x8*)(vb + ((size_t)((c0 >> 4) + nf) * NT32 + 0 * 2 + ks) * 512 + loff);
  {
    s16x8 kn[2];
    for (int ks = 0; ks < 2; ks++)
      kn[ks] = *(const s16x8*)(k_t + ((size_t)(ktb + 1 * 4 + w) * 2 + ks) * 512 + loff);
    f32x4 sc[3];
    for (int mf = 0; mf < 3; mf++) sc[mf] = (f32x4){0.f, 0.f, 0.f, 0.f};
    for (int ks = 0; ks < 2; ks++)
      for (int mf = 0; mf < 3; mf++)
        sc[mf] = __builtin_amdgcn_mfma_f32_16x16x32_bf16(qa[mf][ks], kf[ks], sc[mf], 0, 0, 0);
    char* ebuf = (char*)e_s[0];
    for (int mf = 0; mf < 3; mf++)
      for (int r = 0; r < 4; r++) {
        float e = __expf(sc[mf][r]);
        rs[mf][r] += e;
        int i = 16 * mf + 4 * lq + r;
        int byte = (i * 128 + (16 * w + l15) * 2) ^ ((i & 7) << 4);
        *(unsigned short*)(ebuf + byte) = f2bf(e);
      }
    asm volatile("s_waitcnt lgkmcnt(0)" ::: "memory");
    __builtin_amdgcn_s_barrier();
    __builtin_amdgcn_sched_barrier(0);
    kf[0] = kn[0];
    kf[1] = kn[1];
  }

  // ---- main loop: iteration jt does scores(jt) + PV(jt-1) ----
  for (int jt = 1; jt < NN / 64; jt++) {
    int jtn = (jt < NN / 64 - 1) ? jt + 1 : jt;
    // V(jt) loads — consumed NEXT iteration (full iteration of latency cover)
    s16x8 vfc[2][4];
    for (int ks = 0; ks < 2; ks++)
      for (int nf = 0; nf < 4; nf++)
        vfc[ks][nf] = *(const s16x8*)(vb + ((size_t)((c0 >> 4) + nf) * NT32 + jt * 2 + ks) * 512 + loff);
    // K(jt+1) prefetch
    s16x8 kn[2];
    for (int ks = 0; ks < 2; ks++)
      kn[ks] = *(const s16x8*)(k_t + ((size_t)(ktb + jtn * 4 + w) * 2 + ks) * 512 + loff);
    // scores(jt) with kf (loaded last iteration)
    f32x4 sc[3];
    for (int mf = 0; mf < 3; mf++) sc[mf] = (f32x4){0.f, 0.f, 0.f, 0.f};
    for (int ks = 0; ks < 2; ks++)
      for (int mf = 0; mf < 3; mf++)
        sc[mf] = __builtin_amdgcn_mfma_f32_16x16x32_bf16(qa[mf][ks], kf[ks], sc[mf], 0, 0, 0);
    // exp + rowsum + stash into ebuf[jt&1]
    char* ebuf_w = (char*)e_s[jt & 1];
    for (int mf = 0; mf < 3; mf++)
      for (int r = 0; r < 4; r++) {
        float e = __expf(sc[mf][r]);
        rs[mf][r] += e;
        int i = 16 * mf + 4 * lq + r;
        int byte = (i * 128 + (16 * w + l15) * 2) ^ ((i & 7) << 4);
        *(unsigned short*)(ebuf_w + byte) = f2bf(e);
      }
    // PV(jt-1): operands ready at iteration start (ebuf written before barrier(jt-1),
    // vfp loaded last iteration) — 24 independent MFMAs for the scheduler
    char* ebuf_r = (char*)e_s[(jt - 1) & 1];
    for (int ks = 0; ks < 2; ks++) {
      s16x8 ef[3];
      for (int mf = 0; mf < 3; mf++) {
        int i = 16 * mf + l15;
        int byte = (i * 128 + 64 * ks + 16 * lq) ^ ((i & 7) << 4);
        ef[mf] = *(const s16x8*)(ebuf_r + byte);
      }
      for (int nf = 0; nf < 4; nf++)
        for (int mf = 0; mf < 3; mf++)
          acc[mf][nf] = __builtin_amdgcn_mfma_f32_16x16x32_bf16(ef[mf], vfp[ks][nf], acc[mf][nf], 0, 0, 0);
    }
    // one barrier per iteration: publishes ebuf[jt&1] writes, drains this iter's ds ops
    asm volatile("s_waitcnt lgkmcnt(0)" ::: "memory");
    __builtin_amdgcn_s_barrier();
    __builtin_amdgcn_sched_barrier(0);
    for (int ks = 0; ks < 2; ks++) {
      kf[ks] = kn[ks];
      for (int nf = 0; nf < 4; nf++) vfp[ks][nf] = vfc[ks][nf];
    }
  }

  // ---- epilogue: PV(35) ----
  {
    char* ebuf_r = (char*)e_s[(NN / 64 - 1) & 1];
    for (int ks = 0; ks < 2; ks++) {
      s16x8 ef[3];
      for (int mf = 0; mf < 3; mf++) {
        int i = 16 * mf + l15;
        int byte = (i * 128 + 64 * ks + 16 * lq) ^ ((i & 7) << 4);
        ef[mf] = *(const s16x8*)(ebuf_r + byte);
      }
      for (int nf = 0; nf < 4; nf++)
        for (int mf = 0; mf < 3; mf++)
          acc[mf][nf] = __builtin_amdgcn_mfma_f32_16x16x32_bf16(ef[mf], vfp[ks][nf], acc[mf][nf], 0, 0, 0);
    }
  }

  // rowsum: 16-lane shuffle reduce, then across 4 waves via LDS
  for (int mf = 0; mf < 3; mf++)
    for (int r = 0; r < 4; r++) {
      float v = rs[mf][r];
      v += __shfl_xor(v, 1); v += __shfl_xor(v, 2);
      v += __shfl_xor(v, 4); v += __shfl_xor(v, 8);
      rs[mf][r] = v;
    }
  if (l15 == 0)
    for (int mf = 0; mf < 3; mf++)
      for (int r = 0; r < 4; r++)
        rs_s[w][16 * mf + 4 * lq + r] = rs[mf][r];
  __syncthreads();
  float inv[3][4];
  for (int mf = 0; mf < 3; mf++)
    for (int r = 0; r < 4; r++) {
      int i = 16 * mf + 4 * lq + r;
      inv[mf][r] = 1.0f / (rs_s[0][i] + rs_s[1][i] + rs_s[2][i] + rs_s[3][i]);
    }
  // content = px + attn@v, in-place RMW on px_t (disjoint per lane/block)
  for (int mf = 0; mf < 3; mf++)
    for (int nf = 0; nf < 4; nf++)
      for (int r = 0; r < 4; r++) {
        int i = 16 * mf + 4 * lq + r;
        int bn = b * NN + ib + i;
        int c = c0 + 16 * nf + l15;
        size_t off = ((size_t)(bn >> 4) * CT32 + (c >> 5)) * 512 + (bn & 15) * 32 + (c & 31);
        px_t[off] = f2bf(bf2f(px_t[off]) + acc[mf][nf][r] * inv[mf][r]);
      }
}

// ---------------- FC + fused BN partial stats ----------------
__global__ __launch_bounds__(256, 3) void k_fc(const unsigned short* __restrict__ px_t,
                                               const unsigned short* __restrict__ wfc_t,
                                               const float* __restrict__ bfc,
                                               float* __restrict__ out,
                                               float2* __restrict__ partials) {
  __shared__ float pss[4][32], psq[4][32];
  int cb = blockIdx.x * 32;
  int yb = blockIdx.y;
  int fb = yb * 384;
  int tid = threadIdx.x;
  int w = tid >> 6, l = tid & 63, l15 = l & 15, lq = l >> 4;
  int fw = fb + 96 * w;
  int loff = l15 * 32 + 8 * lq;
  f32x4 acc[2][6];
  for (int mf = 0; mf < 2; mf++) for (int nf = 0; nf < 6; nf++) acc[mf][nf] = (f32x4){0.f, 0.f, 0.f, 0.f};
  for (int kk = 0; kk < 16; kk++) {
    s16x8 a[2], bbf[6];
    for (int mf = 0; mf < 2; mf++)
      a[mf] = *(const s16x8*)(wfc_t + ((size_t)((cb >> 4) + mf) * CT32 + kk) * 512 + loff);
    for (int nf = 0; nf < 6; nf++)
      bbf[nf] = *(const s16x8*)(px_t + ((size_t)((fw >> 4) + nf) * CT32 + kk) * 512 + loff);
    for (int mf = 0; mf < 2; mf++)
      for (int nf = 0; nf < 6; nf++)
        acc[mf][nf] = __builtin_amdgcn_mfma_f32_16x16x32_bf16(a[mf], bbf[nf], acc[mf][nf], 0, 0, 0);
  }
  float s8[2][4], q8[2][4];
  for (int mf = 0; mf < 2; mf++)
    for (int r = 0; r < 4; r++) {
      int c2 = cb + 16 * mf + 4 * lq + r;
      float bias = bfc[c2];
      float s = 0.f, q = 0.f;
      for (int nf = 0; nf < 6; nf++) {
        float v = acc[mf][nf][r] + bias;
        int flat = fw + 16 * nf + l15;
        int b2 = flat / NN;
        int n = flat - b2 * NN;
        out[((size_t)b2 * CC + c2) * NN + n] = v;
        s += v; q += v * v;
      }
      s8[mf][r] = s; q8[mf][r] = q;
    }
  for (int mf = 0; mf < 2; mf++)
    for (int r = 0; r < 4; r++) {
      float s = s8[mf][r], q = q8[mf][r];
      s += __shfl_xor(s, 1); q += __shfl_xor(q, 1);
      s += __shfl_xor(s, 2); q += __shfl_xor(q, 2);
      s += __shfl_xor(s, 4); q += __shfl_xor(q, 4);
      s += __shfl_xor(s, 8); q += __shfl_xor(q, 8);
      s8[mf][r] = s; q8[mf][r] = q;
    }
  if (l15 == 0)
    for (int mf = 0; mf < 2; mf++)
      for (int r = 0; r < 4; r++) {
        int idx = 16 * mf + 4 * lq + r;
        pss[w][idx] = s8[mf][r];
        psq[w][idx] = q8[mf][r];
      }
  __syncthreads();
  if (tid < 32) {
    float s = pss[0][tid] + pss[1][tid] + pss[2][tid] + pss[3][tid];
    float q = psq[0][tid] + psq[1][tid] + psq[2][tid] + psq[3][tid];
    partials[(size_t)(cb + tid) * NYB + yb] = make_float2(s, q);
  }
}

// ---------------- BN stats finalize ----------------
__global__ void k_stats2(const float2* __restrict__ partials, const float* __restrict__ gamma,
                         const float* __restrict__ beta, float2* __restrict__ ab) {
  int c = blockIdx.x * 256 + threadIdx.x;
  if (c >= CC) return;
  float s = 0.f, q = 0.f;
  for (int i = 0; i < NYB; i++) {
    float2 p = partials[(size_t)c * NYB + i];
    s += p.x; q += p.y;
  }
  const float invn = 1.0f / (BB * NN);
  float mean = s * invn;
  float var = q * invn - mean * mean;
  float a = gamma[c] * rsqrtf(var + 1e-5f);
  ab[c] = make_float2(a, beta[c] - mean * a);
}

// ---------------- BN apply + ReLU, in-place on out ----------------
__global__ void k_bn(float* __restrict__ out, const float2* __restrict__ ab) {
  int idx = blockIdx.x * 256 + threadIdx.x;  // float4 index
  const int total = BB * CC * NN / 4;
  if (idx >= total) return;
  int c = (idx / (NN / 4)) & (CC - 1);
  float2 p = ab[c];
  f32x4 v = ((f32x4*)out)[idx];
  for (int i = 0; i < 4; i++) v[i] = fmaxf(0.f, v[i] * p.x + p.y);
  ((f32x4*)out)[idx] = v;
}

extern "C" void kernel_launch(void* const* d_in, const int* in_sizes, int n_in,
                              void* d_out, int out_size, void* d_ws, size_t ws_size,
                              hipStream_t stream) {
  const float* x = (const float*)d_in[0];
  const float* Wq = (const float*)d_in[1];
  const float* Wk = (const float*)d_in[2];
  const float* Wv = (const float*)d_in[3];
  const float* align_w = (const float*)d_in[4];
  const float* Wfc = (const float*)d_in[5];
  const float* bfc = (const float*)d_in[6];
  const float* gamma = (const float*)d_in[7];
  const float* beta = (const float*)d_in[8];
  float* out = (float*)d_out;

  char* ws = (char*)d_ws;
  const size_t sz_px = (size_t)BB * NN * CC * 2;  // px_t / content, in-place
  const size_t sz_q = (size_t)BB * NN * 64 * 2;
  const size_t sz_vr = (size_t)BB * NN * CC * 2;
  unsigned short* px_t = (unsigned short*)(ws);
  unsigned short* q_t = (unsigned short*)(ws + sz_px);
  unsigned short* k_t = (unsigned short*)(ws + sz_px + sz_q);
  unsigned short* v_row = (unsigned short*)(ws + sz_px + 2 * sz_q);
  unsigned short* vt_t = (unsigned short*)(ws + sz_px + 2 * sz_q + sz_vr);
  unsigned short* wcat_t = (unsigned short*)(ws + sz_px + 2 * sz_q + 2 * sz_vr);
  unsigned short* wfc_t = (unsigned short*)(ws + sz_px + 2 * sz_q + 2 * sz_vr + 640 * 512 * 2);
  float2* partials = (float2*)(ws + sz_px + 2 * sz_q + 2 * sz_vr + 640 * 512 * 2 + 512 * 512 * 2);
  float2* ab = (float2*)((char*)partials + (size_t)CC * NYB * sizeof(float2));

  k_prep_w<<<(640 * 512 + 512 * 512 + 255) / 256, 256, 0, stream>>>(Wq, Wk, Wv, Wfc, wcat_t, wfc_t);
  k_px<<<dim3(BB, NN / 32, CC / 32), 256, 0, stream>>>(x, px_t);
  k_qkv<<<dim3(BB, NN / 64, 5), 256, 0, stream>>>(px_t, wcat_t, align_w, q_t, k_t, v_row);
  k_vt<<<dim3(BB, NN / 32, CC / 32), 256, 0, stream>>>(v_row, vt_t);
  k_attn<<<dim3(BB, NN / 48, 2), 256, 0, stream>>>(q_t, k_t, vt_t, px_t);
  k_fc<<<dim3(CC / 32, NYB), 256, 0, stream>>>(px_t, wfc_t, bfc, out, partials);
  k_stats2<<<2, 256, 0, stream>>>(partials, gamma, beta, ab);
  k_bn<<<(BB * CC * NN / 4 + 255) / 256, 256, 0, stream>>>(out, ab);
}

// Round 7
// 191.300 us; speedup vs baseline: 2.1277x; 1.0371x over previous
//
#include <hip/hip_runtime.h>
#include <stdint.h>

#define BB 8
#define CC 512
#define NN 2304
#define NT16 (NN / 16)  // 144
#define NT32 (NN / 32)  // 72
#define CT32 (CC / 32)  // 16
#define NYB 48          // k_fc y-blocks (stats partials)

typedef float f32x4 __attribute__((ext_vector_type(4)));
typedef short s16x8 __attribute__((ext_vector_type(8)));

__device__ __forceinline__ unsigned short f2bf(float f) {
  union { float f; uint32_t u; } v; v.f = f;
  uint32_t u = v.u;
  return (unsigned short)((u + 0x7FFFu + ((u >> 16) & 1u)) >> 16);
}
__device__ __forceinline__ float bf2f(unsigned short b) {
  union { uint32_t u; float f; } v; v.u = ((uint32_t)b) << 16;
  return v.f;
}

// Tiled layout everywhere: buf[row/16][k/32][16][32], 1KB tiles matching the MFMA
// fragment (lane l15 = row, 8*lq = k-offset). Fragment load = one contiguous 1KB
// wave-transaction (R4 win: 217us -> 91us on k_attn).

// ---------------- prep: bf16 [Wq|Wk|Wv] rows -> wcat_t tiles; Wfc -> wfc_t tiles ----------------
__global__ void k_prep_w(const float* __restrict__ Wq, const float* __restrict__ Wk,
                         const float* __restrict__ Wv, const float* __restrict__ Wfc,
                         unsigned short* __restrict__ wcat_t, unsigned short* __restrict__ wfc_t) {
  int idx = blockIdx.x * 256 + threadIdx.x;
  const int tot_cat = 640 * 512;
  if (idx < tot_cat) {
    int tile = idx >> 9, inner = idx & 511;
    int j = (tile >> 4) * 16 + (inner >> 5);
    int k = (tile & 15) * 32 + (inner & 31);
    float v = (j < 64) ? Wq[j * 512 + k] : ((j < 128) ? Wk[(j - 64) * 512 + k] : Wv[(j - 128) * 512 + k]);
    wcat_t[idx] = f2bf(v);
  } else if (idx < tot_cat + 512 * 512) {
    int i2 = idx - tot_cat;
    int tile = i2 >> 9, inner = i2 & 511;
    int j = (tile >> 4) * 16 + (inner >> 5);
    int k = (tile & 15) * 32 + (inner & 31);
    wfc_t[i2] = f2bf(Wfc[j * 512 + k]);
  }
}

// ---------------- px_t[(b*NN+n)/16][c/32][16][32] = bf16(x[b][c][n]) ----------------
__global__ void k_px(const float* __restrict__ x, unsigned short* __restrict__ px_t) {
  __shared__ float t[32][33];
  int b = blockIdx.x;
  int nb = blockIdx.y * 32;
  int cb = blockIdx.z * 32;
  int lane = threadIdx.x & 31;
  int row = threadIdx.x >> 5;  // 0..7
  const float* xb = x + (size_t)b * CC * NN;
  for (int rr = 0; rr < 4; rr++) {
    int c = cb + row + 8 * rr;
    t[row + 8 * rr][lane] = xb[(size_t)c * NN + nb + lane];
  }
  __syncthreads();
  int rbase = (b * NN + nb) >> 4;
  int ct = cb >> 5;
  for (int rr = 0; rr < 4; rr++) {
    int nl = row + 8 * rr;  // 0..31
    size_t off = ((size_t)(rbase + (nl >> 4)) * CT32 + ct) * 512 + (nl & 15) * 32 + lane;
    px_t[off] = f2bf(t[lane][nl]);
  }
}

// ---------------- QKV GEMM: q_t/k_t tiled, v_row row-major; tanh/align fused ----------------
__global__ __launch_bounds__(256, 2) void k_qkv(const unsigned short* __restrict__ px_t,
                                                const unsigned short* __restrict__ wcat_t,
                                                const float* __restrict__ align_w,
                                                unsigned short* __restrict__ q_t,
                                                unsigned short* __restrict__ k_t,
                                                unsigned short* __restrict__ v_row) {
  int b = blockIdx.x;
  int nb = blockIdx.y * 64;
  int jb0 = blockIdx.z * 128;
  int tid = threadIdx.x;
  int w = tid >> 6, l = tid & 63, l15 = l & 15, lq = l >> 4;
  int jw = jb0 + 32 * w;
  int loff = l15 * 32 + 8 * lq;
  int rA = (b * NN + nb) >> 4;
  f32x4 acc[4][2];
  for (int mf = 0; mf < 4; mf++) for (int nf = 0; nf < 2; nf++) acc[mf][nf] = (f32x4){0.f, 0.f, 0.f, 0.f};
  for (int kk = 0; kk < 16; kk++) {
    s16x8 a[4], bbf[2];
    for (int mf = 0; mf < 4; mf++)
      a[mf] = *(const s16x8*)(px_t + ((size_t)(rA + mf) * CT32 + kk) * 512 + loff);
    for (int nf = 0; nf < 2; nf++)
      bbf[nf] = *(const s16x8*)(wcat_t + ((size_t)((jw >> 4) + nf) * CT32 + kk) * 512 + loff);
    for (int mf = 0; mf < 4; mf++)
      for (int nf = 0; nf < 2; nf++)
        acc[mf][nf] = __builtin_amdgcn_mfma_f32_16x16x32_bf16(a[mf], bbf[nf], acc[mf][nf], 0, 0, 0);
  }
  for (int mf = 0; mf < 4; mf++)
    for (int nf = 0; nf < 2; nf++)
      for (int r = 0; r < 4; r++) {
        int j = jw + 16 * nf + l15;
        int nl = 4 * lq + r;
        float v = acc[mf][nf][r];
        if (j < 128) { v = tanhf(v); if (j < 64) v *= align_w[j]; }
        unsigned short bv = f2bf(v);
        if (j < 64)
          q_t[((size_t)(rA + mf) * 2 + (j >> 5)) * 512 + nl * 32 + (j & 31)] = bv;
        else if (j < 128) {
          int jj = j - 64;
          k_t[((size_t)(rA + mf) * 2 + (jj >> 5)) * 512 + nl * 32 + (jj & 31)] = bv;
        } else {
          v_row[((size_t)(b * NN) + nb + 16 * mf + nl) * 512 + (j - 128)] = bv;
        }
      }
}

// ---------------- vt_t[b][c/16][n/32][16][32] = transpose of v_row ----------------
__global__ void k_vt(const unsigned short* __restrict__ v_row, unsigned short* __restrict__ vt_t) {
  __shared__ uint32_t t[32][33];
  int b = blockIdx.x;
  int nb = blockIdx.y * 32;
  int cb = blockIdx.z * 32;
  int lane = threadIdx.x & 31;
  int row = threadIdx.x >> 5;
  const unsigned short* src = v_row + (size_t)b * NN * 512;
  for (int rr = 0; rr < 4; rr++) {
    int n = nb + row + 8 * rr;
    t[row + 8 * rr][lane] = (uint32_t)src[(size_t)n * 512 + cb + lane];
  }
  __syncthreads();
  unsigned short* dst = vt_t + (size_t)b * (CC / 16) * NT32 * 512;
  for (int rr = 0; rr < 4; rr++) {
    int c = cb + row + 8 * rr;
    size_t off = ((size_t)(c >> 4) * NT32 + (nb >> 5)) * 512 + (c & 15) * 32 + lane;
    dst[off] = (unsigned short)t[lane][row + 8 * rr];
  }
}

// ---------------- fused attention, i-tile 48, c-split x2 ----------------
// R7: (a) XCD batch pinning: 1D grid 768, b = bid&7 -> each XCD's L2 caches ONE
// batch's K/V/Q (~3MB < 4MB). (b) swapped QK^T: mfma(K,Q) puts S[i=l15][j=4lq+r]
// lane-local with 4 CONSECUTIVE j per register -> v_cvt_pk_bf16_f32 pairs + one
// ds_write_b64 per mf (3 writes/iter vs 12 b16) and rowsum in 3 scalars.
// (c) unroll-by-2 parity (static ebuf/kf) kills all register-rotation movs.
// (d) s_setprio(1) around MFMA clusters. One raw s_barrier + lgkmcnt(0)/iter.
__global__ __launch_bounds__(256, 3) void k_attn(const unsigned short* __restrict__ q_t,
                                                 const unsigned short* __restrict__ k_t,
                                                 const unsigned short* __restrict__ vt_t,
                                                 unsigned short* __restrict__ px_t /* content in-place */) {
  __shared__ __align__(16) unsigned short e_s[2][48 * 64];
  __shared__ float rs_s[4][48];
  int bid = blockIdx.x;
  int b = bid & 7;           // XCD pin: all blocks on XCD k share batch k
  int ch = ((bid >> 3) & 1) * 256;
  int ib = (bid >> 4) * 48;
  int tid = threadIdx.x;
  int w = tid >> 6, l = tid & 63, l15 = l & 15, lq = l >> 4;
  int c0 = ch + 64 * w;
  int loff = l15 * 32 + 8 * lq;
  int rQ = (b * NN + ib) >> 4;
  int ktb = b * NT16;
  const unsigned short* vb = vt_t + (size_t)b * (CC / 16) * NT32 * 512;

  s16x8 qa[3][2];
  for (int mf = 0; mf < 3; mf++)
    for (int ks = 0; ks < 2; ks++)
      qa[mf][ks] = *(const s16x8*)(q_t + ((size_t)(rQ + mf) * 2 + ks) * 512 + loff);

  f32x4 acc[3][4];
  for (int mf = 0; mf < 3; mf++) for (int nf = 0; nf < 4; nf++) acc[mf][nf] = (f32x4){0.f, 0.f, 0.f, 0.f};
  float rs[3] = {0.f, 0.f, 0.f};

  // K dbuf: kf0 used by even jt, kf1 by odd jt; prefetched one iteration ahead.
  s16x8 kf0[2], kf1[2];
  for (int ks = 0; ks < 2; ks++)
    kf0[ks] = *(const s16x8*)(k_t + ((size_t)(ktb + w) * 2 + ks) * 512 + loff);

  auto step = [&](int jt, char* ebuf, s16x8 (&kfu)[2], s16x8 (&kfl)[2]) {
    int jtn = (jt < NN / 64 - 1) ? jt + 1 : jt;
    // V(jt): 8 coalesced 1KB tile loads, consumed after the barrier this iteration
    s16x8 vf[2][4];
    for (int ks = 0; ks < 2; ks++)
      for (int nf = 0; nf < 4; nf++)
        vf[ks][nf] = *(const s16x8*)(vb + ((size_t)((c0 >> 4) + nf) * NT32 + jt * 2 + ks) * 512 + loff);
    // K(jt+1) prefetch into the other parity's regs
    for (int ks = 0; ks < 2; ks++)
      kfl[ks] = *(const s16x8*)(k_t + ((size_t)(ktb + jtn * 4 + w) * 2 + ks) * 512 + loff);
    // swapped scores: D[row=4lq+r -> j_local][col=l15 -> i_local]
    // lane (l15,lq) reg r = S[i = 16mf+l15][j = jb + 16w + 4lq + r]
    f32x4 sc[3];
    for (int mf = 0; mf < 3; mf++) sc[mf] = (f32x4){0.f, 0.f, 0.f, 0.f};
    __builtin_amdgcn_s_setprio(1);
    for (int ks = 0; ks < 2; ks++)
      for (int mf = 0; mf < 3; mf++)
        sc[mf] = __builtin_amdgcn_mfma_f32_16x16x32_bf16(kfu[ks], qa[mf][ks], sc[mf], 0, 0, 0);
    __builtin_amdgcn_s_setprio(0);
    // exp (|s|<=8, no max), rowsum, pack 4 consecutive j as 2x cvt_pk, 1 b64 write/mf
    for (int mf = 0; mf < 3; mf++) {
      float e0 = __expf(sc[mf][0]), e1 = __expf(sc[mf][1]);
      float e2 = __expf(sc[mf][2]), e3 = __expf(sc[mf][3]);
      rs[mf] += (e0 + e1) + (e2 + e3);
      uint32_t p0, p1;
      asm("v_cvt_pk_bf16_f32 %0, %1, %2" : "=v"(p0) : "v"(e0), "v"(e1));
      asm("v_cvt_pk_bf16_f32 %0, %1, %2" : "=v"(p1) : "v"(e2), "v"(e3));
      int i_ = 16 * mf + l15;
      int byte = (i_ * 128 + (16 * w + 4 * lq) * 2) ^ ((i_ & 7) << 4);
      uint2 pp; pp.x = p0; pp.y = p1;
      *(uint2*)(ebuf + byte) = pp;
    }
    // raw barrier: drain LDS only; global loads stay in flight
    asm volatile("s_waitcnt lgkmcnt(0)" ::: "memory");
    __builtin_amdgcn_s_barrier();
    __builtin_amdgcn_sched_barrier(0);
    // PV(jt): acc[i][c] += e[i][j] * vt[c][j]
    for (int ks = 0; ks < 2; ks++) {
      s16x8 ef[3];
      for (int mf = 0; mf < 3; mf++) {
        int i_ = 16 * mf + l15;
        int byte = (i_ * 128 + 64 * ks + 16 * lq) ^ ((i_ & 7) << 4);
        ef[mf] = *(const s16x8*)((const char*)ebuf + byte);
      }
      __builtin_amdgcn_s_setprio(1);
      for (int nf = 0; nf < 4; nf++)
        for (int mf = 0; mf < 3; mf++)
          acc[mf][nf] = __builtin_amdgcn_mfma_f32_16x16x32_bf16(ef[mf], vf[ks][nf], acc[mf][nf], 0, 0, 0);
      __builtin_amdgcn_s_setprio(0);
    }
    // no trailing barrier: next iter writes the OTHER e_s buffer; this iter's
    // reads are drained by next iter's lgkmcnt(0) before its barrier.
  };

  for (int jt = 0; jt < NN / 64; jt += 2) {
    step(jt, (char*)e_s[0], kf0, kf1);
    step(jt + 1, (char*)e_s[1], kf1, kf0);
  }

  // rowsum: lanes sharing l15 (same i) reduce over lq via shfl 16/32, then cross-wave
  for (int mf = 0; mf < 3; mf++) {
    float v = rs[mf];
    v += __shfl_xor(v, 16);
    v += __shfl_xor(v, 32);
    rs[mf] = v;
  }
  if (lq == 0)
    for (int mf = 0; mf < 3; mf++)
      rs_s[w][16 * mf + l15] = rs[mf];
  __syncthreads();
  float inv[3][4];
  for (int mf = 0; mf < 3; mf++)
    for (int r = 0; r < 4; r++) {
      int i = 16 * mf + 4 * lq + r;
      inv[mf][r] = 1.0f / (rs_s[0][i] + rs_s[1][i] + rs_s[2][i] + rs_s[3][i]);
    }
  // content = px + attn@v, in-place RMW on px_t (disjoint per lane/block)
  for (int mf = 0; mf < 3; mf++)
    for (int nf = 0; nf < 4; nf++)
      for (int r = 0; r < 4; r++) {
        int i = 16 * mf + 4 * lq + r;
        int bn = b * NN + ib + i;
        int c = c0 + 16 * nf + l15;
        size_t off = ((size_t)(bn >> 4) * CT32 + (c >> 5)) * 512 + (bn & 15) * 32 + (c & 31);
        px_t[off] = f2bf(bf2f(px_t[off]) + acc[mf][nf][r] * inv[mf][r]);
      }
}

// ---------------- FC + fused BN partial stats ----------------
__global__ __launch_bounds__(256, 3) void k_fc(const unsigned short* __restrict__ px_t,
                                               const unsigned short* __restrict__ wfc_t,
                                               const float* __restrict__ bfc,
                                               float* __restrict__ out,
                                               float2* __restrict__ partials) {
  __shared__ float pss[4][32], psq[4][32];
  int cb = blockIdx.x * 32;
  int yb = blockIdx.y;
  int fb = yb * 384;
  int tid = threadIdx.x;
  int w = tid >> 6, l = tid & 63, l15 = l & 15, lq = l >> 4;
  int fw = fb + 96 * w;
  int loff = l15 * 32 + 8 * lq;
  f32x4 acc[2][6];
  for (int mf = 0; mf < 2; mf++) for (int nf = 0; nf < 6; nf++) acc[mf][nf] = (f32x4){0.f, 0.f, 0.f, 0.f};
  for (int kk = 0; kk < 16; kk++) {
    s16x8 a[2], bbf[6];
    for (int mf = 0; mf < 2; mf++)
      a[mf] = *(const s16x8*)(wfc_t + ((size_t)((cb >> 4) + mf) * CT32 + kk) * 512 + loff);
    for (int nf = 0; nf < 6; nf++)
      bbf[nf] = *(const s16x8*)(px_t + ((size_t)((fw >> 4) + nf) * CT32 + kk) * 512 + loff);
    for (int mf = 0; mf < 2; mf++)
      for (int nf = 0; nf < 6; nf++)
        acc[mf][nf] = __builtin_amdgcn_mfma_f32_16x16x32_bf16(a[mf], bbf[nf], acc[mf][nf], 0, 0, 0);
  }
  float s8[2][4], q8[2][4];
  for (int mf = 0; mf < 2; mf++)
    for (int r = 0; r < 4; r++) {
      int c2 = cb + 16 * mf + 4 * lq + r;
      float bias = bfc[c2];
      float s = 0.f, q = 0.f;
      for (int nf = 0; nf < 6; nf++) {
        float v = acc[mf][nf][r] + bias;
        int flat = fw + 16 * nf + l15;
        int b2 = flat / NN;
        int n = flat - b2 * NN;
        out[((size_t)b2 * CC + c2) * NN + n] = v;
        s += v; q += v * v;
      }
      s8[mf][r] = s; q8[mf][r] = q;
    }
  for (int mf = 0; mf < 2; mf++)
    for (int r = 0; r < 4; r++) {
      float s = s8[mf][r], q = q8[mf][r];
      s += __shfl_xor(s, 1); q += __shfl_xor(q, 1);
      s += __shfl_xor(s, 2); q += __shfl_xor(q, 2);
      s += __shfl_xor(s, 4); q += __shfl_xor(q, 4);
      s += __shfl_xor(s, 8); q += __shfl_xor(q, 8);
      s8[mf][r] = s; q8[mf][r] = q;
    }
  if (l15 == 0)
    for (int mf = 0; mf < 2; mf++)
      for (int r = 0; r < 4; r++) {
        int idx = 16 * mf + 4 * lq + r;
        pss[w][idx] = s8[mf][r];
        psq[w][idx] = q8[mf][r];
      }
  __syncthreads();
  if (tid < 32) {
    float s = pss[0][tid] + pss[1][tid] + pss[2][tid] + pss[3][tid];
    float q = psq[0][tid] + psq[1][tid] + psq[2][tid] + psq[3][tid];
    partials[(size_t)(cb + tid) * NYB + yb] = make_float2(s, q);
  }
}

// ---------------- BN stats finalize ----------------
__global__ void k_stats2(const float2* __restrict__ partials, const float* __restrict__ gamma,
                         const float* __restrict__ beta, float2* __restrict__ ab) {
  int c = blockIdx.x * 256 + threadIdx.x;
  if (c >= CC) return;
  float s = 0.f, q = 0.f;
  for (int i = 0; i < NYB; i++) {
    float2 p = partials[(size_t)c * NYB + i];
    s += p.x; q += p.y;
  }
  const float invn = 1.0f / (BB * NN);
  float mean = s * invn;
  float var = q * invn - mean * mean;
  float a = gamma[c] * rsqrtf(var + 1e-5f);
  ab[c] = make_float2(a, beta[c] - mean * a);
}

// ---------------- BN apply + ReLU, in-place on out ----------------
__global__ void k_bn(float* __restrict__ out, const float2* __restrict__ ab) {
  int idx = blockIdx.x * 256 + threadIdx.x;  // float4 index
  const int total = BB * CC * NN / 4;
  if (idx >= total) return;
  int c = (idx / (NN / 4)) & (CC - 1);
  float2 p = ab[c];
  f32x4 v = ((f32x4*)out)[idx];
  for (int i = 0; i < 4; i++) v[i] = fmaxf(0.f, v[i] * p.x + p.y);
  ((f32x4*)out)[idx] = v;
}

extern "C" void kernel_launch(void* const* d_in, const int* in_sizes, int n_in,
                              void* d_out, int out_size, void* d_ws, size_t ws_size,
                              hipStream_t stream) {
  const float* x = (const float*)d_in[0];
  const float* Wq = (const float*)d_in[1];
  const float* Wk = (const float*)d_in[2];
  const float* Wv = (const float*)d_in[3];
  const float* align_w = (const float*)d_in[4];
  const float* Wfc = (const float*)d_in[5];
  const float* bfc = (const float*)d_in[6];
  const float* gamma = (const float*)d_in[7];
  const float* beta = (const float*)d_in[8];
  float* out = (float*)d_out;

  char* ws = (char*)d_ws;
  const size_t sz_px = (size_t)BB * NN * CC * 2;  // px_t / content, in-place
  const size_t sz_q = (size_t)BB * NN * 64 * 2;
  const size_t sz_vr = (size_t)BB * NN * CC * 2;
  unsigned short* px_t = (unsigned short*)(ws);
  unsigned short* q_t = (unsigned short*)(ws + sz_px);
  unsigned short* k_t = (unsigned short*)(ws + sz_px + sz_q);
  unsigned short* v_row = (unsigned short*)(ws + sz_px + 2 * sz_q);
  unsigned short* vt_t = (unsigned short*)(ws + sz_px + 2 * sz_q + sz_vr);
  unsigned short* wcat_t = (unsigned short*)(ws + sz_px + 2 * sz_q + 2 * sz_vr);
  unsigned short* wfc_t = (unsigned short*)(ws + sz_px + 2 * sz_q + 2 * sz_vr + 640 * 512 * 2);
  float2* partials = (float2*)(ws + sz_px + 2 * sz_q + 2 * sz_vr + 640 * 512 * 2 + 512 * 512 * 2);
  float2* ab = (float2*)((char*)partials + (size_t)CC * NYB * sizeof(float2));

  k_prep_w<<<(640 * 512 + 512 * 512 + 255) / 256, 256, 0, stream>>>(Wq, Wk, Wv, Wfc, wcat_t, wfc_t);
  k_px<<<dim3(BB, NN / 32, CC / 32), 256, 0, stream>>>(x, px_t);
  k_qkv<<<dim3(BB, NN / 64, 5), 256, 0, stream>>>(px_t, wcat_t, align_w, q_t, k_t, v_row);
  k_vt<<<dim3(BB, NN / 32, CC / 32), 256, 0, stream>>>(v_row, vt_t);
  k_attn<<<768, 256, 0, stream>>>(q_t, k_t, vt_t, px_t);
  k_fc<<<dim3(CC / 32, NYB), 256, 0, stream>>>(px_t, wfc_t, bfc, out, partials);
  k_stats2<<<2, 256, 0, stream>>>(partials, gamma, beta, ab);
  k_bn<<<(BB * CC * NN / 4 + 255) / 256, 256, 0, stream>>>(out, ab);
}

// Round 8
// 171.241 us; speedup vs baseline: 2.3769x; 1.1171x over previous
//
#include <hip/hip_runtime.h>
#include <stdint.h>

#define BB 8
#define CC 512
#define NN 2304
#define NT16 (NN / 16)  // 144
#define NT32 (NN / 32)  // 72
#define CT32 (CC / 32)  // 16
#define NYB 48          // k_fc y-blocks (stats partials)

typedef float f32x4 __attribute__((ext_vector_type(4)));
typedef short s16x8 __attribute__((ext_vector_type(8)));

__device__ __forceinline__ unsigned short f2bf(float f) {
  union { float f; uint32_t u; } v; v.f = f;
  uint32_t u = v.u;
  return (unsigned short)((u + 0x7FFFu + ((u >> 16) & 1u)) >> 16);
}
__device__ __forceinline__ float bf2f(unsigned short b) {
  union { uint32_t u; float f; } v; v.u = ((uint32_t)b) << 16;
  return v.f;
}
__device__ __forceinline__ uint32_t cvtpk(float lo, float hi) {
  uint32_t r;
  asm("v_cvt_pk_bf16_f32 %0, %1, %2" : "=v"(r) : "v"(lo), "v"(hi));
  return r;
}

// Tiled layout everywhere: buf[row/16][k/32][16][32], 1KB tiles matching the MFMA
// fragment (lane l15 = row, 8*lq = k-offset) -> fragment load = one contiguous
// 1KB wave transaction (R4 win). R8: k_vt fused into k_qkv; k_fc emits bf16.

// ---------------- prep: bf16 [Wq|Wk|Wv] rows -> wcat_t tiles; Wfc -> wfc_t tiles ----------------
__global__ void k_prep_w(const float* __restrict__ Wq, const float* __restrict__ Wk,
                         const float* __restrict__ Wv, const float* __restrict__ Wfc,
                         unsigned short* __restrict__ wcat_t, unsigned short* __restrict__ wfc_t) {
  int idx = blockIdx.x * 256 + threadIdx.x;
  const int tot_cat = 640 * 512;
  if (idx < tot_cat) {
    int tile = idx >> 9, inner = idx & 511;
    int j = (tile >> 4) * 16 + (inner >> 5);
    int k = (tile & 15) * 32 + (inner & 31);
    float v = (j < 64) ? Wq[j * 512 + k] : ((j < 128) ? Wk[(j - 64) * 512 + k] : Wv[(j - 128) * 512 + k]);
    wcat_t[idx] = f2bf(v);
  } else if (idx < tot_cat + 512 * 512) {
    int i2 = idx - tot_cat;
    int tile = i2 >> 9, inner = i2 & 511;
    int j = (tile >> 4) * 16 + (inner >> 5);
    int k = (tile & 15) * 32 + (inner & 31);
    wfc_t[i2] = f2bf(Wfc[j * 512 + k]);
  }
}

// ---------------- px_t[(b*NN+n)/16][c/32][16][32] = bf16(x[b][c][n]) ----------------
// gridDim.x = 8 (fastest-varying) -> b == XCD id automatically.
__global__ void k_px(const float* __restrict__ x, unsigned short* __restrict__ px_t) {
  __shared__ float t[32][33];
  int b = blockIdx.x;
  int nb = blockIdx.y * 32;
  int cb = blockIdx.z * 32;
  int lane = threadIdx.x & 31;
  int row = threadIdx.x >> 5;  // 0..7
  const float* xb = x + (size_t)b * CC * NN;
  for (int rr = 0; rr < 4; rr++) {
    int c = cb + row + 8 * rr;
    t[row + 8 * rr][lane] = xb[(size_t)c * NN + nb + lane];
  }
  __syncthreads();
  int rbase = (b * NN + nb) >> 4;
  int ct = cb >> 5;
  for (int rr = 0; rr < 4; rr++) {
    int nl = row + 8 * rr;  // 0..31
    size_t off = ((size_t)(rbase + (nl >> 4)) * CT32 + ct) * 512 + (nl & 15) * 32 + lane;
    px_t[off] = f2bf(t[lane][nl]);
  }
}

// ---------------- QKV GEMM, z=3: z0 -> q_t+k_t (tanh/align), z1,2 -> vt_t DIRECT ----------------
// 1D grid 864 = 8b x 36nb x 3z, b = bid&7 (XCD pin: A-slab 2.4MB + W 0.7MB in one L2).
// V written straight into the transposed-tiled vt_t layout: a C-fragment's 4 r-values
// are 4 consecutive n at fixed c = 4 consecutive shorts in vt_t's inner [32] dim ->
// cvt_pk x2 + one 8B store per (mf,nf). k_vt kernel eliminated.
__global__ __launch_bounds__(256, 2) void k_qkv(const unsigned short* __restrict__ px_t,
                                                const unsigned short* __restrict__ wcat_t,
                                                const float* __restrict__ align_w,
                                                unsigned short* __restrict__ q_t,
                                                unsigned short* __restrict__ k_t,
                                                unsigned short* __restrict__ vt_t) {
  int bid = blockIdx.x;
  int b = bid & 7;
  int t = bid >> 3;        // 0..107
  int z = t % 3;
  int nb = (t / 3) * 64;
  int tid = threadIdx.x;
  int w = tid >> 6, l = tid & 63, l15 = l & 15, lq = l >> 4;
  int loff = l15 * 32 + 8 * lq;
  int rA = (b * NN + nb) >> 4;
  int nfmax = (z == 0) ? 2 : 4;
  int rowB0 = (z == 0) ? 2 * w : 8 + (z - 1) * 16 + 4 * w;  // wcat_t row-tile base
  f32x4 acc[4][4];
  for (int mf = 0; mf < 4; mf++) for (int nf = 0; nf < 4; nf++) acc[mf][nf] = (f32x4){0.f, 0.f, 0.f, 0.f};
  for (int kk = 0; kk < 16; kk++) {
    s16x8 a[4], bbf[4];
    for (int mf = 0; mf < 4; mf++)
      a[mf] = *(const s16x8*)(px_t + ((size_t)(rA + mf) * CT32 + kk) * 512 + loff);
    for (int nf = 0; nf < 4; nf++)
      if (nf < nfmax)
        bbf[nf] = *(const s16x8*)(wcat_t + ((size_t)(rowB0 + nf) * CT32 + kk) * 512 + loff);
    for (int mf = 0; mf < 4; mf++)
      for (int nf = 0; nf < 4; nf++)
        if (nf < nfmax)
          acc[mf][nf] = __builtin_amdgcn_mfma_f32_16x16x32_bf16(a[mf], bbf[nf], acc[mf][nf], 0, 0, 0);
  }
  if (z == 0) {
    // j = 32w + 16nf + l15; w<2 -> q (j<64), w>=2 -> k
    for (int mf = 0; mf < 4; mf++)
      for (int nf = 0; nf < 2; nf++)
        for (int r = 0; r < 4; r++) {
          int j = 32 * w + 16 * nf + l15;
          int nl = 4 * lq + r;
          float v = tanhf(acc[mf][nf][r]);
          if (w < 2) {
            v *= align_w[j];
            q_t[((size_t)(rA + mf) * 2 + w) * 512 + nl * 32 + (j & 31)] = f2bf(v);
          } else {
            k_t[((size_t)(rA + mf) * 2 + (w - 2)) * 512 + nl * 32 + (j & 31)] = f2bf(v);
          }
        }
  } else {
    // c = (z-1)*256 + 64w + 16nf + l15 ; n = nb + 16mf + 4lq + r (r=0..3 consecutive)
    unsigned short* vtb = vt_t + (size_t)b * (CC / 16) * NT32 * 512;
    for (int mf = 0; mf < 4; mf++)
      for (int nf = 0; nf < 4; nf++) {
        int c = (z - 1) * 256 + 64 * w + 16 * nf + l15;
        uint2 pp;
        pp.x = cvtpk(acc[mf][nf][0], acc[mf][nf][1]);
        pp.y = cvtpk(acc[mf][nf][2], acc[mf][nf][3]);
        int nlo = 16 * (mf & 1) + 4 * lq;
        size_t off = ((size_t)(c >> 4) * NT32 + (nb >> 5) + (mf >> 1)) * 512 + (c & 15) * 32 + nlo;
        *(uint2*)(vtb + off) = pp;
      }
  }
}

// ---------------- fused attention, i-tile 48, c-split x2 (R7 structure, unchanged) ----------------
__global__ __launch_bounds__(256, 3) void k_attn(const unsigned short* __restrict__ q_t,
                                                 const unsigned short* __restrict__ k_t,
                                                 const unsigned short* __restrict__ vt_t,
                                                 unsigned short* __restrict__ px_t /* content in-place */) {
  __shared__ __align__(16) unsigned short e_s[2][48 * 64];
  __shared__ float rs_s[4][48];
  int bid = blockIdx.x;
  int b = bid & 7;           // XCD pin
  int ch = ((bid >> 3) & 1) * 256;
  int ib = (bid >> 4) * 48;
  int tid = threadIdx.x;
  int w = tid >> 6, l = tid & 63, l15 = l & 15, lq = l >> 4;
  int c0 = ch + 64 * w;
  int loff = l15 * 32 + 8 * lq;
  int rQ = (b * NN + ib) >> 4;
  int ktb = b * NT16;
  const unsigned short* vb = vt_t + (size_t)b * (CC / 16) * NT32 * 512;

  s16x8 qa[3][2];
  for (int mf = 0; mf < 3; mf++)
    for (int ks = 0; ks < 2; ks++)
      qa[mf][ks] = *(const s16x8*)(q_t + ((size_t)(rQ + mf) * 2 + ks) * 512 + loff);

  f32x4 acc[3][4];
  for (int mf = 0; mf < 3; mf++) for (int nf = 0; nf < 4; nf++) acc[mf][nf] = (f32x4){0.f, 0.f, 0.f, 0.f};
  float rs[3] = {0.f, 0.f, 0.f};

  s16x8 kf0[2], kf1[2];
  for (int ks = 0; ks < 2; ks++)
    kf0[ks] = *(const s16x8*)(k_t + ((size_t)(ktb + w) * 2 + ks) * 512 + loff);

  auto step = [&](int jt, char* ebuf, s16x8 (&kfu)[2], s16x8 (&kfl)[2]) {
    int jtn = (jt < NN / 64 - 1) ? jt + 1 : jt;
    s16x8 vf[2][4];
    for (int ks = 0; ks < 2; ks++)
      for (int nf = 0; nf < 4; nf++)
        vf[ks][nf] = *(const s16x8*)(vb + ((size_t)((c0 >> 4) + nf) * NT32 + jt * 2 + ks) * 512 + loff);
    for (int ks = 0; ks < 2; ks++)
      kfl[ks] = *(const s16x8*)(k_t + ((size_t)(ktb + jtn * 4 + w) * 2 + ks) * 512 + loff);
    f32x4 sc[3];
    for (int mf = 0; mf < 3; mf++) sc[mf] = (f32x4){0.f, 0.f, 0.f, 0.f};
    __builtin_amdgcn_s_setprio(1);
    for (int ks = 0; ks < 2; ks++)
      for (int mf = 0; mf < 3; mf++)
        sc[mf] = __builtin_amdgcn_mfma_f32_16x16x32_bf16(kfu[ks], qa[mf][ks], sc[mf], 0, 0, 0);
    __builtin_amdgcn_s_setprio(0);
    for (int mf = 0; mf < 3; mf++) {
      float e0 = __expf(sc[mf][0]), e1 = __expf(sc[mf][1]);
      float e2 = __expf(sc[mf][2]), e3 = __expf(sc[mf][3]);
      rs[mf] += (e0 + e1) + (e2 + e3);
      uint2 pp;
      pp.x = cvtpk(e0, e1);
      pp.y = cvtpk(e2, e3);
      int i_ = 16 * mf + l15;
      int byte = (i_ * 128 + (16 * w + 4 * lq) * 2) ^ ((i_ & 7) << 4);
      *(uint2*)(ebuf + byte) = pp;
    }
    asm volatile("s_waitcnt lgkmcnt(0)" ::: "memory");
    __builtin_amdgcn_s_barrier();
    __builtin_amdgcn_sched_barrier(0);
    for (int ks = 0; ks < 2; ks++) {
      s16x8 ef[3];
      for (int mf = 0; mf < 3; mf++) {
        int i_ = 16 * mf + l15;
        int byte = (i_ * 128 + 64 * ks + 16 * lq) ^ ((i_ & 7) << 4);
        ef[mf] = *(const s16x8*)((const char*)ebuf + byte);
      }
      __builtin_amdgcn_s_setprio(1);
      for (int nf = 0; nf < 4; nf++)
        for (int mf = 0; mf < 3; mf++)
          acc[mf][nf] = __builtin_amdgcn_mfma_f32_16x16x32_bf16(ef[mf], vf[ks][nf], acc[mf][nf], 0, 0, 0);
      __builtin_amdgcn_s_setprio(0);
    }
  };

  for (int jt = 0; jt < NN / 64; jt += 2) {
    step(jt, (char*)e_s[0], kf0, kf1);
    step(jt + 1, (char*)e_s[1], kf1, kf0);
  }

  for (int mf = 0; mf < 3; mf++) {
    float v = rs[mf];
    v += __shfl_xor(v, 16);
    v += __shfl_xor(v, 32);
    rs[mf] = v;
  }
  if (lq == 0)
    for (int mf = 0; mf < 3; mf++)
      rs_s[w][16 * mf + l15] = rs[mf];
  __syncthreads();
  float inv[3][4];
  for (int mf = 0; mf < 3; mf++)
    for (int r = 0; r < 4; r++) {
      int i = 16 * mf + 4 * lq + r;
      inv[mf][r] = 1.0f / (rs_s[0][i] + rs_s[1][i] + rs_s[2][i] + rs_s[3][i]);
    }
  for (int mf = 0; mf < 3; mf++)
    for (int nf = 0; nf < 4; nf++)
      for (int r = 0; r < 4; r++) {
        int i = 16 * mf + 4 * lq + r;
        int bn = b * NN + ib + i;
        int c = c0 + 16 * nf + l15;
        size_t off = ((size_t)(bn >> 4) * CT32 + (c >> 5)) * 512 + (bn & 15) * 32 + (c & 31);
        px_t[off] = f2bf(bf2f(px_t[off]) + acc[mf][nf][r] * inv[mf][r]);
      }
}

// ---------------- FC + fused BN partial stats; bf16 output c16 ----------------
// 1D grid 768: xcd = bid&7 pins yb (px slab 2.4MB/XCD); yb = (bid&7)+8*((bid>>3)%6),
// cb = ((bid>>3)/6)*32.
__global__ __launch_bounds__(256, 3) void k_fc(const unsigned short* __restrict__ px_t,
                                               const unsigned short* __restrict__ wfc_t,
                                               const float* __restrict__ bfc,
                                               unsigned short* __restrict__ c16,
                                               float2* __restrict__ partials) {
  __shared__ float pss[4][32], psq[4][32];
  int bid = blockIdx.x;
  int s_ = bid >> 3;
  int yb = (bid & 7) + 8 * (s_ % 6);
  int cb = (s_ / 6) * 32;
  int fb = yb * 384;
  int tid = threadIdx.x;
  int w = tid >> 6, l = tid & 63, l15 = l & 15, lq = l >> 4;
  int fw = fb + 96 * w;
  int loff = l15 * 32 + 8 * lq;
  f32x4 acc[2][6];
  for (int mf = 0; mf < 2; mf++) for (int nf = 0; nf < 6; nf++) acc[mf][nf] = (f32x4){0.f, 0.f, 0.f, 0.f};
  for (int kk = 0; kk < 16; kk++) {
    s16x8 a[2], bbf[6];
    for (int mf = 0; mf < 2; mf++)
      a[mf] = *(const s16x8*)(wfc_t + ((size_t)((cb >> 4) + mf) * CT32 + kk) * 512 + loff);
    for (int nf = 0; nf < 6; nf++)
      bbf[nf] = *(const s16x8*)(px_t + ((size_t)((fw >> 4) + nf) * CT32 + kk) * 512 + loff);
    for (int mf = 0; mf < 2; mf++)
      for (int nf = 0; nf < 6; nf++)
        acc[mf][nf] = __builtin_amdgcn_mfma_f32_16x16x32_bf16(a[mf], bbf[nf], acc[mf][nf], 0, 0, 0);
  }
  float s8[2][4], q8[2][4];
  for (int mf = 0; mf < 2; mf++)
    for (int r = 0; r < 4; r++) {
      int c2 = cb + 16 * mf + 4 * lq + r;
      float bias = bfc[c2];
      float s = 0.f, q = 0.f;
      for (int nf = 0; nf < 6; nf++) {
        float v = acc[mf][nf][r] + bias;
        int flat = fw + 16 * nf + l15;
        int b2 = flat / NN;
        int n = flat - b2 * NN;
        c16[((size_t)b2 * CC + c2) * NN + n] = f2bf(v);
        s += v; q += v * v;
      }
      s8[mf][r] = s; q8[mf][r] = q;
    }
  for (int mf = 0; mf < 2; mf++)
    for (int r = 0; r < 4; r++) {
      float s = s8[mf][r], q = q8[mf][r];
      s += __shfl_xor(s, 1); q += __shfl_xor(q, 1);
      s += __shfl_xor(s, 2); q += __shfl_xor(q, 2);
      s += __shfl_xor(s, 4); q += __shfl_xor(q, 4);
      s += __shfl_xor(s, 8); q += __shfl_xor(q, 8);
      s8[mf][r] = s; q8[mf][r] = q;
    }
  if (l15 == 0)
    for (int mf = 0; mf < 2; mf++)
      for (int r = 0; r < 4; r++) {
        int idx = 16 * mf + 4 * lq + r;
        pss[w][idx] = s8[mf][r];
        psq[w][idx] = q8[mf][r];
      }
  __syncthreads();
  if (tid < 32) {
    float s = pss[0][tid] + pss[1][tid] + pss[2][tid] + pss[3][tid];
    float q = psq[0][tid] + psq[1][tid] + psq[2][tid] + psq[3][tid];
    partials[(size_t)(cb + tid) * NYB + yb] = make_float2(s, q);
  }
}

// ---------------- BN stats finalize ----------------
__global__ void k_stats2(const float2* __restrict__ partials, const float* __restrict__ gamma,
                         const float* __restrict__ beta, float2* __restrict__ ab) {
  int c = blockIdx.x * 256 + threadIdx.x;
  if (c >= CC) return;
  float s = 0.f, q = 0.f;
  for (int i = 0; i < NYB; i++) {
    float2 p = partials[(size_t)c * NYB + i];
    s += p.x; q += p.y;
  }
  const float invn = 1.0f / (BB * NN);
  float mean = s * invn;
  float var = q * invn - mean * mean;
  float a = gamma[c] * rsqrtf(var + 1e-5f);
  ab[c] = make_float2(a, beta[c] - mean * a);
}

// ---------------- BN apply + ReLU: read bf16 c16, write fp32 out ----------------
__global__ void k_bn(const unsigned short* __restrict__ c16, float* __restrict__ out,
                     const float2* __restrict__ ab) {
  int idx = blockIdx.x * 256 + threadIdx.x;  // ushort8 index
  const int total = BB * CC * NN / 8;
  if (idx >= total) return;
  int c = (idx / (NN / 8)) & (CC - 1);
  float2 p = ab[c];
  s16x8 v = ((const s16x8*)c16)[idx];
  f32x4 o0, o1;
  for (int i = 0; i < 4; i++) o0[i] = fmaxf(0.f, bf2f((unsigned short)v[i]) * p.x + p.y);
  for (int i = 0; i < 4; i++) o1[i] = fmaxf(0.f, bf2f((unsigned short)v[4 + i]) * p.x + p.y);
  ((f32x4*)out)[idx * 2] = o0;
  ((f32x4*)out)[idx * 2 + 1] = o1;
}

extern "C" void kernel_launch(void* const* d_in, const int* in_sizes, int n_in,
                              void* d_out, int out_size, void* d_ws, size_t ws_size,
                              hipStream_t stream) {
  const float* x = (const float*)d_in[0];
  const float* Wq = (const float*)d_in[1];
  const float* Wk = (const float*)d_in[2];
  const float* Wv = (const float*)d_in[3];
  const float* align_w = (const float*)d_in[4];
  const float* Wfc = (const float*)d_in[5];
  const float* bfc = (const float*)d_in[6];
  const float* gamma = (const float*)d_in[7];
  const float* beta = (const float*)d_in[8];
  float* out = (float*)d_out;

  char* ws = (char*)d_ws;
  const size_t sz_px = (size_t)BB * NN * CC * 2;  // px_t / content, in-place
  const size_t sz_q = (size_t)BB * NN * 64 * 2;
  const size_t sz_vr = (size_t)BB * NN * CC * 2;
  unsigned short* px_t = (unsigned short*)(ws);
  unsigned short* q_t = (unsigned short*)(ws + sz_px);
  unsigned short* k_t = (unsigned short*)(ws + sz_px + sz_q);
  unsigned short* c16 = (unsigned short*)(ws + sz_px + 2 * sz_q);          // old v_row slot
  unsigned short* vt_t = (unsigned short*)(ws + sz_px + 2 * sz_q + sz_vr);
  unsigned short* wcat_t = (unsigned short*)(ws + sz_px + 2 * sz_q + 2 * sz_vr);
  unsigned short* wfc_t = (unsigned short*)(ws + sz_px + 2 * sz_q + 2 * sz_vr + 640 * 512 * 2);
  float2* partials = (float2*)(ws + sz_px + 2 * sz_q + 2 * sz_vr + 640 * 512 * 2 + 512 * 512 * 2);
  float2* ab = (float2*)((char*)partials + (size_t)CC * NYB * sizeof(float2));

  k_prep_w<<<(640 * 512 + 512 * 512 + 255) / 256, 256, 0, stream>>>(Wq, Wk, Wv, Wfc, wcat_t, wfc_t);
  k_px<<<dim3(BB, NN / 32, CC / 32), 256, 0, stream>>>(x, px_t);
  k_qkv<<<864, 256, 0, stream>>>(px_t, wcat_t, align_w, q_t, k_t, vt_t);
  k_attn<<<768, 256, 0, stream>>>(q_t, k_t, vt_t, px_t);
  k_fc<<<768, 256, 0, stream>>>(px_t, wfc_t, bfc, c16, partials);
  k_stats2<<<2, 256, 0, stream>>>(partials, gamma, beta, ab);
  k_bn<<<(BB * CC * NN / 8 + 255) / 256, 256, 0, stream>>>(c16, out, ab);
}